// Round 3
// baseline (212.389 us; speedup 1.0000x reference)
//
#include <hip/hip_runtime.h>
#include <math.h>

#define BB 2
#define NN 256
#define EE 512
#define PP 256
#define DD 128
#define TT 8
#define KK 8
#define HDIM 256

// workspace offsets (floats)
#define WS_G      0          // B*E*K = 8192
#define WS_C0     8192       // 1 (+pad)
#define WS_EF0    8256       // B*E*D = 131072   (ef_init, later ete)
#define WS_U1     139328     // B*E*HD = 262144  (U1 then U2)
#define WS_V      401472     // B*N*HD = 131072
#define WS_HW     532544     // B*E*N = 262144   level-1 Hw (row-major)
#define WS_HWT    794688     // B*N*E = 262144   level-2 Hw2 TRANSPOSED [b][n][e]
#define WS_EDGEF  1056832    // B*E*D = 131072
#define WS_ETYPE  1187904    // B*E*T = 8192
#define WS_AGF    1196096    // B*N*3D = 196608
#define WS_Q2     1392704    // 65536
#define WS_K2     1458240    // 65536
#define WS_V2     1523776    // 65536
// total 1589312 floats = 6.36 MB

__device__ inline unsigned rotl32(unsigned x, int d){ return (x<<d)|(x>>(32-d)); }

__device__ inline float bits_to_gumbel(unsigned bits){
  float f = __uint_as_float((bits>>9)|0x3f800000u) - 1.0f;
  const float minv = 1e-6f;
  const float maxv = 1.0f - 1e-6f;
  float u = f*(maxv-minv) + minv;
  u = fmaxf(minv, u);
  return -logf(-logf(u));
}

// ---- block-wide reduction of 4 values over 256 threads (4 waves) ----
__device__ __forceinline__ void block_reduce4_max(float v[4], float* wred){
  int lane = threadIdx.x & 63, wid = threadIdx.x >> 6;
  #pragma unroll
  for (int s=32;s>0;s>>=1){
    #pragma unroll
    for (int r=0;r<4;r++){ float o = __shfl_xor(v[r], s, 64); v[r] = fmaxf(v[r],o); }
  }
  if (lane==0){
    #pragma unroll
    for (int r=0;r<4;r++) wred[wid*4+r]=v[r];
  }
  __syncthreads();
  #pragma unroll
  for (int r=0;r<4;r++)
    v[r] = fmaxf(fmaxf(wred[0*4+r],wred[1*4+r]), fmaxf(wred[2*4+r],wred[3*4+r]));
  __syncthreads();
}

__device__ __forceinline__ void block_reduce4_sum(float v[4], float* wred){
  int lane = threadIdx.x & 63, wid = threadIdx.x >> 6;
  #pragma unroll
  for (int s=32;s>0;s>>=1){
    #pragma unroll
    for (int r=0;r<4;r++){ v[r] += __shfl_xor(v[r], s, 64); }
  }
  if (lane==0){
    #pragma unroll
    for (int r=0;r<4;r++) wred[wid*4+r]=v[r];
  }
  __syncthreads();
  #pragma unroll
  for (int r=0;r<4;r++)
    v[r] = (wred[0*4+r]+wred[1*4+r]) + (wred[2*4+r]+wred[3*4+r]);
  __syncthreads();
}

// K1: threefry2x32-20 gumbel noise + c0 = relu(b1)@W2 + b2
__global__ void gumbel_kernel(float* g, float* c0, const float* w_b1,
                              const float* w_W2, const float* w_b2){
  int j = blockIdx.x*blockDim.x + threadIdx.x;
  if (j < 4096) {
    const unsigned k0=0u, k1=42u;
    const unsigned ks2 = k0^k1^0x1BD11BDAu;
    unsigned x0 = (unsigned)j, x1 = (unsigned)j + 4096u;
    const int r0[4]={13,15,26,6}, r1[4]={17,29,16,24};
    x0 += k0; x1 += k1;
    #pragma unroll
    for(int i=0;i<4;i++){ x0+=x1; x1=rotl32(x1,r0[i]); x1^=x0; }
    x0+=k1; x1+=ks2+1u;
    #pragma unroll
    for(int i=0;i<4;i++){ x0+=x1; x1=rotl32(x1,r1[i]); x1^=x0; }
    x0+=ks2; x1+=k0+2u;
    #pragma unroll
    for(int i=0;i<4;i++){ x0+=x1; x1=rotl32(x1,r0[i]); x1^=x0; }
    x0+=k0; x1+=k1+3u;
    #pragma unroll
    for(int i=0;i<4;i++){ x0+=x1; x1=rotl32(x1,r1[i]); x1^=x0; }
    x0+=k1; x1+=ks2+4u;
    #pragma unroll
    for(int i=0;i<4;i++){ x0+=x1; x1=rotl32(x1,r0[i]); x1^=x0; }
    x0+=ks2; x1+=k0+5u;
    g[j]        = bits_to_gumbel(x0);
    g[j+4096]   = bits_to_gumbel(x1);
  }
  if (blockIdx.x==0 && threadIdx.x==0){
    float s = 0.f;
    for (int h=0;h<HDIM;h++) s += fmaxf(w_b1[h],0.f)*w_W2[h];
    c0[0] = s + w_b2[0];
  }
}

// K2: ef_init = H@af ; edge_type = H@at  (compact-then-stream)
__global__ void incidence_kernel(const float* Hm, const float* af, const float* at,
                                 float* ef0, float* etype){
  __shared__ int ecomp[NN];
  __shared__ int wcnt[2];
  int be = blockIdx.x;
  int d  = threadIdx.x;           // 128 (2 waves)
  int b  = be / EE;
  int lane = d & 63, wid = d >> 6;
  const float* Hrow = Hm + (size_t)be*NN;
  int total = 0;
  #pragma unroll
  for (int p=0;p<2;p++){
    int n = p*128 + d;
    bool pred = (Hrow[n] != 0.f);
    unsigned long long mask = __ballot(pred);
    if (lane==0) wcnt[wid] = __popcll(mask);
    int off = __popcll(mask & ((1ull<<lane)-1ull));
    __syncthreads();
    int wb = total + (wid==1 ? wcnt[0] : 0);
    if (pred) ecomp[wb+off] = n;
    total += wcnt[0]+wcnt[1];
    __syncthreads();
  }
  float acc = 0.f, acct = 0.f;
  for (int i=0;i<total;i++){
    int n = ecomp[i];
    acc += af[((size_t)b*NN+n)*DD + d];
    if (d < TT) acct += at[((size_t)b*NN+n)*TT + d];
  }
  ef0[(size_t)be*DD+d] = acc;
  if (d < TT) etype[(size_t)be*TT+d] = acct;
}

// K3: merged U1 (1024 rows) + V (512 rows) row-MLPs, R=4 rows/block
__global__ void uv_mlp_kernel(const float* ef0, const float* afm, const float* wW1,
                              const float* wb1, float* U1, float* Vout){
  __shared__ float xs[4][DD];
  int t = threadIdx.x;            // 256
  const float* src; const float* W; const float* bias; float* dst; int r0;
  if (blockIdx.x < 256){ src=ef0; W=wW1; bias=wb1; dst=U1; r0=blockIdx.x*4; }
  else { src=afm; W=wW1 + (size_t)DD*HDIM; bias=nullptr; dst=Vout; r0=(blockIdx.x-256)*4; }
  for (int i=t;i<4*DD;i+=256) xs[i>>7][i&127] = src[(size_t)(r0+(i>>7))*DD + (i&127)];
  __syncthreads();
  float bv = bias ? bias[t] : 0.f;
  float acc[4]={bv,bv,bv,bv};
  #pragma unroll 4
  for (int i=0;i<DD;i++){
    float w = W[(size_t)i*HDIM + t];
    #pragma unroll
    for (int r=0;r<4;r++) acc[r]+=xs[r][i]*w;
  }
  #pragma unroll
  for (int r=0;r<4;r++) dst[(size_t)(r0+r)*HDIM + t] = acc[r];
}

// standalone R=4 row-MLP (for U2 = ete@W1[:D]+b1)
__global__ void rowmlp4_kernel(const float* src, const float* W, const float* bias, float* dst){
  __shared__ float xs[4][DD];
  int t = threadIdx.x;
  int r0 = blockIdx.x*4;
  for (int i=t;i<4*DD;i+=256) xs[i>>7][i&127] = src[(size_t)(r0+(i>>7))*DD + (i&127)];
  __syncthreads();
  float bv = bias ? bias[t] : 0.f;
  float acc[4]={bv,bv,bv,bv};
  #pragma unroll 4
  for (int i=0;i<DD;i++){
    float w = W[(size_t)i*HDIM + t];
    #pragma unroll
    for (int r=0;r<4;r++) acc[r]+=xs[r][i]*w;
  }
  #pragma unroll
  for (int r=0;r<4;r++) dst[(size_t)(r0+r)*HDIM + t] = acc[r];
}

// K4: level-1 relu-dot + masked softmax, R=4 edges/block
__global__ void ew_softmax4_kernel(const float* U1, const float* Vm, const float* Hm,
                                   const float* w_W2, const float* w_b2, float* Hw){
  __shared__ float u[4][HDIM];
  __shared__ float w2[HDIM];
  __shared__ float wred[16];
  int e0 = blockIdx.x*4;
  int b = e0 >> 9;                 // /EE
  int n = threadIdx.x;             // 256
  for (int i=n;i<4*HDIM;i+=256) u[i>>8][i&255] = U1[(size_t)(e0+(i>>8))*HDIM + (i&255)];
  w2[n] = w_W2[n];
  __syncthreads();
  const float4* Vrow = (const float4*)(Vm + ((size_t)(b*NN)+n)*HDIM);
  float acc[4]={0.f,0.f,0.f,0.f};
  #pragma unroll 4
  for (int ii=0;ii<HDIM/4;ii++){
    float4 v = Vrow[ii];
    float w0=w2[4*ii+0], w1=w2[4*ii+1], wc=w2[4*ii+2], w3=w2[4*ii+3];
    #pragma unroll
    for (int r=0;r<4;r++){
      acc[r] += fmaxf(u[r][4*ii+0]+v.x,0.f)*w0
              + fmaxf(u[r][4*ii+1]+v.y,0.f)*w1
              + fmaxf(u[r][4*ii+2]+v.z,0.f)*wc
              + fmaxf(u[r][4*ii+3]+v.w,0.f)*w3;
    }
  }
  float b2v = w_b2[0];
  float x[4], hv[4];
  #pragma unroll
  for (int r=0;r<4;r++){
    hv[r] = Hm[(size_t)(e0+r)*NN + n];
    x[r] = (hv[r]!=0.f) ? (acc[r]+b2v) : 0.f;
  }
  float m4[4]={x[0],x[1],x[2],x[3]};
  block_reduce4_max(m4, wred);
  float p4[4];
  #pragma unroll
  for (int r=0;r<4;r++) p4[r]=expf(x[r]-m4[r]);
  float s4[4]={p4[0],p4[1],p4[2],p4[3]};
  block_reduce4_sum(s4, wred);
  #pragma unroll
  for (int r=0;r<4;r++)
    Hw[(size_t)(e0+r)*NN + n] = (hv[r]!=0.f) ? p4[r]/s4[r] : 0.f;
}

// K5: edge_features = Hw@af (compact-then-stream)
__global__ void aggregate_kernel(const float* Wgt, const float* af, float* outp){
  __shared__ int   ecomp[NN];
  __shared__ float wcomp[NN];
  __shared__ int wcnt[2];
  int be = blockIdx.x; int d = threadIdx.x; int b = be/EE;   // 128 threads
  int lane = d & 63, wid = d >> 6;
  const float* wrow = Wgt + (size_t)be*NN;
  int total = 0;
  #pragma unroll
  for (int p=0;p<2;p++){
    int n = p*128 + d;
    float w = wrow[n];
    bool pred = (w != 0.f);
    unsigned long long mask = __ballot(pred);
    if (lane==0) wcnt[wid] = __popcll(mask);
    int off = __popcll(mask & ((1ull<<lane)-1ull));
    __syncthreads();
    int wb = total + (wid==1 ? wcnt[0] : 0);
    if (pred){ ecomp[wb+off] = n; wcomp[wb+off] = w; }
    total += wcnt[0]+wcnt[1];
    __syncthreads();
  }
  float acc = 0.f;
  for (int i=0;i<total;i++){
    acc += wcomp[i]*af[((size_t)b*NN+ecomp[i])*DD + d];
  }
  outp[(size_t)be*DD + d] = acc;
}

// K6: typed edge embedding, R=4 edges/block
__global__ void type4_kernel(const float* edgef, const float* etype, const float* g,
                             const float* dW1, const float* db1, const float* dW2, const float* db2,
                             const float* fW1, const float* fb1, const float* fW2, const float* fb2,
                             const float* type_emb, float* ete){
  __shared__ float et[4][DD+TT];
  __shared__ float hd[4][HDIM];
  __shared__ float part[256];
  __shared__ float w2s[HDIM*KK];
  __shared__ float wred[16];
  __shared__ float facs[4];
  __shared__ float zz[4][KK];
  __shared__ float pzs[4][KK];
  __shared__ float fdv[4][KK];
  int e0 = blockIdx.x*4; int t = threadIdx.x;   // 256
  #pragma unroll
  for (int r=0;r<4;r++){
    if (t < DD) et[r][t] = edgef[(size_t)(e0+r)*DD + t];
    else if (t < DD+TT) et[r][t] = etype[(size_t)(e0+r)*TT + (t-DD)];
  }
  for (int i=t;i<HDIM*KK;i+=256) w2s[i] = dW2[i];
  __syncthreads();
  float ad[4], afv[4];
  float bd = db1[t], bf = fb1[t];
  #pragma unroll
  for (int r=0;r<4;r++){ ad[r]=bd; afv[r]=bf; }
  #pragma unroll 2
  for (int i=0;i<DD+TT;i++){
    float wd = dW1[(size_t)i*HDIM+t];
    float wf = fW1[(size_t)i*HDIM+t];
    #pragma unroll
    for (int r=0;r<4;r++){ float xx = et[r][i]; ad[r]+=xx*wd; afv[r]+=xx*wf; }
  }
  #pragma unroll
  for (int r=0;r<4;r++) hd[r][t] = fmaxf(ad[r],0.f);
  float fw = fW2[t];
  float v4[4];
  #pragma unroll
  for (int r=0;r<4;r++) v4[r] = fmaxf(afv[r],0.f)*fw;
  block_reduce4_sum(v4, wred);     // syncs inside make hd visible too
  if (t==0){
    float fb2v = fb2[0];
    facs[0] = 1.f/(1.f+expf(-(v4[0]+fb2v)));
    facs[1] = 1.f/(1.f+expf(-(v4[1]+fb2v)));
    facs[2] = 1.f/(1.f+expf(-(v4[2]+fb2v)));
    facs[3] = 1.f/(1.f+expf(-(v4[3]+fb2v)));
  }
  // logits: t -> (r=t>>6, k=(t>>3)&7, j=t&7), partial over 32 h
  int rr_ = t>>6, kk_ = (t>>3)&7, jj_ = t&7;
  float lp = 0.f;
  #pragma unroll 4
  for (int h=jj_*32; h<jj_*32+32; h++) lp += hd[rr_][h]*w2s[h*KK + kk_];
  part[t] = lp;
  __syncthreads();
  if (t < 32){
    int r = t>>3, k = t&7;
    float s = db2[k] + g[(size_t)(e0+r)*KK + k];
    #pragma unroll
    for (int j=0;j<8;j++) s += part[(r<<6)|(k<<3)|j];
    zz[r][k] = s*2.0f;               // /tau, tau=0.5
  }
  __syncthreads();
  if (t < 32){
    int r = t>>3, k = t&7;
    float m = zz[r][0];
    #pragma unroll
    for (int k2=1;k2<KK;k2++) m = fmaxf(m, zz[r][k2]);
    pzs[r][k] = expf(zz[r][k]-m);
  }
  __syncthreads();
  if (t < 32){
    int r = t>>3, k = t&7;
    float s = 0.f;
    #pragma unroll
    for (int k2=0;k2<KK;k2++) s += pzs[r][k2];
    fdv[r][k] = facs[r]*pzs[r][k]/s;
  }
  __syncthreads();
  int d = t&127;
  #pragma unroll
  for (int rr=0;rr<2;rr++){
    int r = 2*rr + (t>>7);
    float acc = 0.f;
    #pragma unroll
    for (int k=0;k<KK;k++) acc += fdv[r][k]*type_emb[(size_t)k*DD + d];
    ete[(size_t)(e0+r)*DD + d] = acc;
  }
}

// K8: level-2 relu-dot + leaky + full softmax, R=4; writes TRANSPOSED Hw2T[b][n][e]
__global__ void hw2_softmax4_kernel(const float* U2, const float* Vm, const float* Hm,
                                    const float* w_W2, const float* w_b2, const float* c0p,
                                    float* HwT){
  __shared__ float u[4][HDIM];
  __shared__ float w2[HDIM];
  __shared__ float wred[16];
  int e0 = blockIdx.x*4;
  int b = e0 >> 9;
  int n = threadIdx.x;
  for (int i=n;i<4*HDIM;i+=256) u[i>>8][i&255] = U2[(size_t)(e0+(i>>8))*HDIM + (i&255)];
  w2[n] = w_W2[n];
  __syncthreads();
  const float4* Vrow = (const float4*)(Vm + ((size_t)(b*NN)+n)*HDIM);
  float acc[4]={0.f,0.f,0.f,0.f};
  #pragma unroll 4
  for (int ii=0;ii<HDIM/4;ii++){
    float4 v = Vrow[ii];
    float w0=w2[4*ii+0], w1=w2[4*ii+1], wc=w2[4*ii+2], w3=w2[4*ii+3];
    #pragma unroll
    for (int r=0;r<4;r++){
      acc[r] += fmaxf(u[r][4*ii+0]+v.x,0.f)*w0
              + fmaxf(u[r][4*ii+1]+v.y,0.f)*w1
              + fmaxf(u[r][4*ii+2]+v.z,0.f)*wc
              + fmaxf(u[r][4*ii+3]+v.w,0.f)*w3;
    }
  }
  float b2v = w_b2[0];
  float c0 = c0p[0];
  float x[4], hv[4];
  #pragma unroll
  for (int r=0;r<4;r++){
    hv[r] = Hm[(size_t)(e0+r)*NN + n];
    float raw = (hv[r]!=0.f) ? (acc[r]+b2v) : c0;
    x[r] = raw>0.f ? raw : 0.01f*raw;        // leaky relu
  }
  float m4[4]={x[0],x[1],x[2],x[3]};
  block_reduce4_max(m4, wred);
  float p4[4];
  #pragma unroll
  for (int r=0;r<4;r++) p4[r]=expf(x[r]-m4[r]);
  float s4[4]={p4[0],p4[1],p4[2],p4[3]};
  block_reduce4_sum(s4, wred);
  int eb = e0 & 511;                         // local e within batch
  float4 o4;
  o4.x = (hv[0]!=0.f)? p4[0]/s4[0] : 0.f;
  o4.y = (hv[1]!=0.f)? p4[1]/s4[1] : 0.f;
  o4.z = (hv[2]!=0.f)? p4[2]/s4[2] : 0.f;
  o4.w = (hv[3]!=0.f)? p4[3]/s4[3] : 0.f;
  *(float4*)(HwT + ((size_t)(b*NN)+n)*EE + eb) = o4;
}

// K9: msg via transposed Hw2T (coalesced scan) + compaction
__global__ void msg_kernel(const float* HwT, const float* edgef, const float* ete,
                           const float* af, float* agf){
  __shared__ int   ecomp[EE];
  __shared__ float wcomp[EE];
  __shared__ int wcnt[4];
  int bn = blockIdx.x; int b = bn>>8; int f = threadIdx.x; // 256 (4 waves)
  int lane = f & 63, wid = f >> 6;
  const float* wrow = HwT + (size_t)bn*EE;
  int total = 0;
  #pragma unroll
  for (int p=0;p<2;p++){
    int e = p*256 + f;
    float w = wrow[e];
    bool pred = (w != 0.f);
    unsigned long long mask = __ballot(pred);
    if (lane==0) wcnt[wid] = __popcll(mask);
    int off = __popcll(mask & ((1ull<<lane)-1ull));
    __syncthreads();
    int wb = total;
    for (int ww=0; ww<wid; ww++) wb += wcnt[ww];
    if (pred){ ecomp[wb+off] = e; wcomp[wb+off] = w; }
    total += wcnt[0]+wcnt[1]+wcnt[2]+wcnt[3];
    __syncthreads();
  }
  float acc = 0.f;
  const float* srcbase = (f < DD) ? (edgef + (size_t)b*EE*DD + f)
                                  : (ete   + (size_t)b*EE*DD + (f-DD));
  for (int i=0;i<total;i++){
    acc += wcomp[i] * srcbase[(size_t)ecomp[i]*DD];
  }
  agf[(size_t)bn*(3*DD)+f] = acc;
  if (f < DD) agf[(size_t)bn*(3*DD) + 2*DD + f] = af[(size_t)bn*DD + f];
}

// K10: merged q2 (blocks 0..127) and k2/v2 (blocks 128..255), R=4, split-k over 2 halves
__global__ void q2kv_kernel(const float* agf, const float* qW, const float* qb,
                            const float* iqW, const float* iqb,
                            const float* pf,
                            const float* kW, const float* kb, const float* ikW, const float* ikb,
                            const float* vW, const float* vb, const float* ivW, const float* ivb,
                            float* q2, float* k2, float* v2){
  __shared__ float part2[2][4][DD];
  int t = threadIdx.x;             // 256
  int d = t & 127, hh = t >> 7;
  if (blockIdx.x < 128){
    __shared__ float xs[4][3*DD];
    __shared__ float Qs[4][DD];
    int r0 = blockIdx.x*4;
    #pragma unroll
    for (int r=0;r<4;r++)
      for (int c=t;c<3*DD;c+=256) xs[r][c] = agf[(size_t)(r0+r)*(3*DD)+c];
    __syncthreads();
    float a1[4]={0.f,0.f,0.f,0.f};
    #pragma unroll 4
    for (int i=hh*192; i<hh*192+192; i++){
      float w = qW[(size_t)i*DD + d];
      #pragma unroll
      for (int r=0;r<4;r++) a1[r]+=xs[r][i]*w;
    }
    #pragma unroll
    for (int r=0;r<4;r++) part2[hh][r][d]=a1[r];
    __syncthreads();
    if (t<DD){
      #pragma unroll
      for (int r=0;r<4;r++) Qs[r][t] = part2[0][r][t]+part2[1][r][t]+qb[t];
    }
    __syncthreads();
    float a2[4]={0.f,0.f,0.f,0.f};
    #pragma unroll 4
    for (int i=hh*64;i<hh*64+64;i++){
      float w = iqW[(size_t)i*DD+d];
      #pragma unroll
      for (int r=0;r<4;r++) a2[r]+=Qs[r][i]*w;
    }
    #pragma unroll
    for (int r=0;r<4;r++) part2[hh][r][d]=a2[r];
    __syncthreads();
    if (t<DD){
      #pragma unroll
      for (int r=0;r<4;r++)
        q2[(size_t)(r0+r)*DD+t] = part2[0][r][t]+part2[1][r][t]+iqb[t];
    }
  } else {
    __shared__ float xk[4][DD];
    __shared__ float tk[4][DD];
    int r0 = (blockIdx.x-128)*4;
    for (int i=t;i<4*DD;i+=256) xk[i>>7][i&127] = pf[(size_t)(r0+(i>>7))*DD + (i&127)];
    __syncthreads();
    // K chain
    float a1[4]={0.f,0.f,0.f,0.f};
    #pragma unroll 4
    for (int i=hh*64;i<hh*64+64;i++){
      float w = kW[(size_t)i*DD+d];
      #pragma unroll
      for (int r=0;r<4;r++) a1[r]+=xk[r][i]*w;
    }
    #pragma unroll
    for (int r=0;r<4;r++) part2[hh][r][d]=a1[r];
    __syncthreads();
    if (t<DD){
      #pragma unroll
      for (int r=0;r<4;r++) tk[r][t]=part2[0][r][t]+part2[1][r][t]+kb[t];
    }
    __syncthreads();
    float a2[4]={0.f,0.f,0.f,0.f};
    #pragma unroll 4
    for (int i=hh*64;i<hh*64+64;i++){
      float w = ikW[(size_t)i*DD+d];
      #pragma unroll
      for (int r=0;r<4;r++) a2[r]+=tk[r][i]*w;
    }
    #pragma unroll
    for (int r=0;r<4;r++) part2[hh][r][d]=a2[r];
    __syncthreads();
    if (t<DD){
      #pragma unroll
      for (int r=0;r<4;r++)
        k2[(size_t)(r0+r)*DD+t] = part2[0][r][t]+part2[1][r][t]+ikb[t];
    }
    __syncthreads();
    // V chain
    float a3[4]={0.f,0.f,0.f,0.f};
    #pragma unroll 4
    for (int i=hh*64;i<hh*64+64;i++){
      float w = vW[(size_t)i*DD+d];
      #pragma unroll
      for (int r=0;r<4;r++) a3[r]+=xk[r][i]*w;
    }
    #pragma unroll
    for (int r=0;r<4;r++) part2[hh][r][d]=a3[r];
    __syncthreads();
    if (t<DD){
      #pragma unroll
      for (int r=0;r<4;r++) tk[r][t]=part2[0][r][t]+part2[1][r][t]+vb[t];
    }
    __syncthreads();
    float a4[4]={0.f,0.f,0.f,0.f};
    #pragma unroll 4
    for (int i=hh*64;i<hh*64+64;i++){
      float w = ivW[(size_t)i*DD+d];
      #pragma unroll
      for (int r=0;r<4;r++) a4[r]+=tk[r][i]*w;
    }
    #pragma unroll
    for (int r=0;r<4;r++) part2[hh][r][d]=a4[r];
    __syncthreads();
    if (t<DD){
      #pragma unroll
      for (int r=0;r<4;r++)
        v2[(size_t)(r0+r)*DD+t] = part2[0][r][t]+part2[1][r][t]+ivb[t];
    }
  }
}

// K10c: 4-head cross attention + out-proj, R=4 q-rows/block
__global__ void attn4_kernel(const float* q2, const float* k2, const float* v2,
                             const float* op_W, const float* op_b, float* pnew){
  __shared__ float qr[4][DD];
  __shared__ float att[4][4][PP+1];   // +1 pad: kill 8-way bank conflict on PV broadcast
  __shared__ float o_l[4][DD];
  int r0 = blockIdx.x*4; int b = r0 >> 8; int t = threadIdx.x; // 256, t = p index
  for (int i=t;i<4*DD;i+=256) qr[i>>7][i&127] = q2[(size_t)(r0+(i>>7))*DD + (i&127)];
  __syncthreads();
  const float scale = 0.17677669529663687f;  // 1/sqrt(32)
  const float* krow = k2 + ((size_t)(b*PP) + t)*DD;
  #pragma unroll
  for (int h=0;h<4;h++){
    const float4* k4 = (const float4*)(krow + h*32);
    float s[4]={0.f,0.f,0.f,0.f};
    #pragma unroll
    for (int jj=0;jj<8;jj++){
      float4 kk = k4[jj];
      #pragma unroll
      for (int r=0;r<4;r++){
        s[r] += qr[r][h*32+jj*4+0]*kk.x + qr[r][h*32+jj*4+1]*kk.y
              + qr[r][h*32+jj*4+2]*kk.z + qr[r][h*32+jj*4+3]*kk.w;
      }
    }
    #pragma unroll
    for (int r=0;r<4;r++) att[r][h][t] = s[r]*scale;
  }
  __syncthreads();
  {
    int lane = t & 63, wid = t >> 6;
    for (int q = wid; q < 16; q += 4){
      int r = q >> 2, h = q & 3;
      float v0 = att[r][h][lane],     v1 = att[r][h][lane+64],
            ve = att[r][h][lane+128], v3 = att[r][h][lane+192];
      float m = fmaxf(fmaxf(v0,v1), fmaxf(ve,v3));
      #pragma unroll
      for (int s2=32;s2>0;s2>>=1) m = fmaxf(m, __shfl_xor(m, s2, 64));
      float e0 = expf(v0-m), e1 = expf(v1-m), e2 = expf(ve-m), e3 = expf(v3-m);
      float ss = (e0+e1)+(e2+e3);
      #pragma unroll
      for (int s2=32;s2>0;s2>>=1) ss += __shfl_xor(ss, s2, 64);
      float inv = 1.f/ss;
      att[r][h][lane] = e0*inv; att[r][h][lane+64] = e1*inv;
      att[r][h][lane+128] = e2*inv; att[r][h][lane+192] = e3*inv;
    }
  }
  __syncthreads();
  int d = t & 127, hh = t >> 7;
  int h2 = d >> 5;
  float oa = 0.f, ob = 0.f;
  #pragma unroll 4
  for (int p=0;p<PP;p++){
    float vv = v2[((size_t)(b*PP)+p)*DD + d];
    oa += att[hh][h2][p]*vv;
    ob += att[2+hh][h2][p]*vv;
  }
  o_l[hh][d] = oa; o_l[2+hh][d] = ob;
  __syncthreads();
  float pa = 0.f, pb = 0.f;
  #pragma unroll 4
  for (int i=0;i<DD;i++){
    float w = op_W[(size_t)i*DD + d];
    pa += o_l[hh][i]*w;
    pb += o_l[2+hh][i]*w;
  }
  pnew[(size_t)(r0+hh)*DD + d]   = pa + op_b[d];
  pnew[(size_t)(r0+2+hh)*DD + d] = pb + op_b[d];
}

// K11: agent_new = MLP([agf, pnew]), R=4 rows/block, split-k stage 2
__global__ void final4_kernel(const float* agf, const float* pnewv,
                              const float* oW1, const float* ob1,
                              const float* oW2, const float* ob2, float* anew){
  __shared__ float xs[4][4*DD];
  __shared__ float hid[4][HDIM];
  __shared__ float part2[2][4][DD];
  int r0 = blockIdx.x*4; int t = threadIdx.x;   // 256
  for (int i=t;i<4*(4*DD);i+=256){
    int r = i>>9, c = i&511;
    xs[r][c] = (c<3*DD) ? agf[(size_t)(r0+r)*(3*DD)+c]
                        : pnewv[(size_t)(r0+r)*DD + (c-3*DD)];
  }
  __syncthreads();
  float bv = ob1[t];
  float acc[4]={bv,bv,bv,bv};
  #pragma unroll 4
  for (int i=0;i<4*DD;i++){
    float w = oW1[(size_t)i*HDIM+t];
    #pragma unroll
    for (int r=0;r<4;r++) acc[r]+=xs[r][i]*w;
  }
  #pragma unroll
  for (int r=0;r<4;r++) hid[r][t]=fmaxf(acc[r],0.f);
  __syncthreads();
  int d = t&127, hh = t>>7;
  float a2[4]={0.f,0.f,0.f,0.f};
  #pragma unroll 4
  for (int h=hh*128; h<hh*128+128; h++){
    float w = oW2[(size_t)h*DD+d];
    #pragma unroll
    for (int r=0;r<4;r++) a2[r]+=hid[r][h]*w;
  }
  #pragma unroll
  for (int r=0;r<4;r++) part2[hh][r][d]=a2[r];
  __syncthreads();
  if (t<DD){
    #pragma unroll
    for (int r=0;r<4;r++)
      anew[(size_t)(r0+r)*DD+t] = part2[0][r][t]+part2[1][r][t]+ob2[t];
  }
}

extern "C" void kernel_launch(void* const* d_in, const int* in_sizes, int n_in,
                              void* d_out, int out_size, void* d_ws, size_t ws_size,
                              hipStream_t stream) {
  const float* af       = (const float*)d_in[0];
  const float* at       = (const float*)d_in[1];
  const float* pf       = (const float*)d_in[2];
  const float* Hm       = (const float*)d_in[3];
  const float* type_emb = (const float*)d_in[4];
  const float* w_W1 = (const float*)d_in[5];
  const float* w_b1 = (const float*)d_in[6];
  const float* w_W2 = (const float*)d_in[7];
  const float* w_b2 = (const float*)d_in[8];
  const float* d_W1 = (const float*)d_in[9];
  const float* d_b1 = (const float*)d_in[10];
  const float* d_W2 = (const float*)d_in[11];
  const float* d_b2 = (const float*)d_in[12];
  const float* f_W1 = (const float*)d_in[13];
  const float* f_b1 = (const float*)d_in[14];
  const float* f_W2 = (const float*)d_in[15];
  const float* f_b2 = (const float*)d_in[16];
  const float* o_W1 = (const float*)d_in[17];
  const float* o_b1 = (const float*)d_in[18];
  const float* o_W2 = (const float*)d_in[19];
  const float* o_b2 = (const float*)d_in[20];
  const float* q_W  = (const float*)d_in[21];
  const float* q_b  = (const float*)d_in[22];
  const float* k_W  = (const float*)d_in[23];
  const float* k_b  = (const float*)d_in[24];
  const float* v_W  = (const float*)d_in[25];
  const float* v_b  = (const float*)d_in[26];
  const float* iq_W = (const float*)d_in[27];
  const float* iq_b = (const float*)d_in[28];
  const float* ik_W = (const float*)d_in[29];
  const float* ik_b = (const float*)d_in[30];
  const float* iv_W = (const float*)d_in[31];
  const float* iv_b = (const float*)d_in[32];
  const float* op_W = (const float*)d_in[33];
  const float* op_b = (const float*)d_in[34];

  float* ws   = (float*)d_ws;
  float* out  = (float*)d_out;
  float* anew = out;                 // (B,N,D)
  float* pnew = out + BB*NN*DD;      // (B,N,D)

  gumbel_kernel<<<16,256,0,stream>>>(ws+WS_G, ws+WS_C0, w_b1, w_W2, w_b2);
  incidence_kernel<<<BB*EE,128,0,stream>>>(Hm, af, at, ws+WS_EF0, ws+WS_ETYPE);
  uv_mlp_kernel<<<384,256,0,stream>>>(ws+WS_EF0, af, w_W1, w_b1, ws+WS_U1, ws+WS_V);
  ew_softmax4_kernel<<<256,256,0,stream>>>(ws+WS_U1, ws+WS_V, Hm, w_W2, w_b2, ws+WS_HW);
  aggregate_kernel<<<BB*EE,128,0,stream>>>(ws+WS_HW, af, ws+WS_EDGEF);
  type4_kernel<<<256,256,0,stream>>>(ws+WS_EDGEF, ws+WS_ETYPE, ws+WS_G,
                                     d_W1,d_b1,d_W2,d_b2, f_W1,f_b1,f_W2,f_b2,
                                     type_emb, ws+WS_EF0 /*ete*/);
  rowmlp4_kernel<<<256,256,0,stream>>>(ws+WS_EF0, w_W1, w_b1, ws+WS_U1 /*U2*/);
  hw2_softmax4_kernel<<<256,256,0,stream>>>(ws+WS_U1, ws+WS_V, Hm, w_W2, w_b2,
                                            ws+WS_C0, ws+WS_HWT);
  msg_kernel<<<BB*NN,256,0,stream>>>(ws+WS_HWT, ws+WS_EDGEF, ws+WS_EF0, af, ws+WS_AGF);
  q2kv_kernel<<<256,256,0,stream>>>(ws+WS_AGF, q_W,q_b,iq_W,iq_b, pf,
                                    k_W,k_b,ik_W,ik_b, v_W,v_b,iv_W,iv_b,
                                    ws+WS_Q2, ws+WS_K2, ws+WS_V2);
  attn4_kernel<<<128,256,0,stream>>>(ws+WS_Q2, ws+WS_K2, ws+WS_V2, op_W, op_b, pnew);
  final4_kernel<<<128,256,0,stream>>>(ws+WS_AGF, pnew, o_W1,o_b1,o_W2,o_b2, anew);
}

// Round 4
// 131.343 us; speedup vs baseline: 1.6171x; 1.6171x over previous
//
#include <hip/hip_runtime.h>
#include <math.h>

#define BB 2
#define NN 256
#define EE 512
#define PP 256
#define DD 128
#define TT 8
#define KK 8
#define HDIM 256

// workspace offsets (floats)
#define WS_G      0          // B*E*K = 8192
#define WS_C0     8192       // 1 (+pad)
#define WS_EF0    8256       // B*E*D = 131072   (ef_init, later ete)
#define WS_U1     139328     // B*E*HD = 262144  (U1 then U2)
#define WS_V      401472     // B*N*HD = 131072
#define WS_HW     532544     // B*E*N = 262144   level-1 Hw (row-major)
#define WS_HWT    794688     // B*N*E = 262144   level-2 Hw2 TRANSPOSED [b][n][e]
#define WS_EDGEF  1056832    // B*E*D = 131072
#define WS_ETYPE  1187904    // B*E*T = 8192
#define WS_AGF    1196096    // B*N*3D = 196608
#define WS_Q2     1392704    // 65536
#define WS_K2     1458240    // 65536
#define WS_V2     1523776    // 65536
// total 1589312 floats = 6.36 MB

__device__ inline unsigned rotl32(unsigned x, int d){ return (x<<d)|(x>>(32-d)); }

__device__ inline float bits_to_gumbel(unsigned bits){
  float f = __uint_as_float((bits>>9)|0x3f800000u) - 1.0f;
  const float minv = 1e-6f;
  const float maxv = 1.0f - 1e-6f;
  float u = f*(maxv-minv) + minv;
  u = fmaxf(minv, u);
  return -logf(-logf(u));
}

__device__ __forceinline__ void f4fma(float4& a, float x, const float4& w){
  a.x += x*w.x; a.y += x*w.y; a.z += x*w.z; a.w += x*w.w;
}

// ---- block-wide reduction of 4 values over 256 threads (4 waves) ----
__device__ __forceinline__ void block_reduce4_max(float v[4], float* wred){
  int lane = threadIdx.x & 63, wid = threadIdx.x >> 6;
  #pragma unroll
  for (int s=32;s>0;s>>=1){
    #pragma unroll
    for (int r=0;r<4;r++){ float o = __shfl_xor(v[r], s, 64); v[r] = fmaxf(v[r],o); }
  }
  if (lane==0){
    #pragma unroll
    for (int r=0;r<4;r++) wred[wid*4+r]=v[r];
  }
  __syncthreads();
  #pragma unroll
  for (int r=0;r<4;r++)
    v[r] = fmaxf(fmaxf(wred[0*4+r],wred[1*4+r]), fmaxf(wred[2*4+r],wred[3*4+r]));
  __syncthreads();
}

__device__ __forceinline__ void block_reduce4_sum(float v[4], float* wred){
  int lane = threadIdx.x & 63, wid = threadIdx.x >> 6;
  #pragma unroll
  for (int s=32;s>0;s>>=1){
    #pragma unroll
    for (int r=0;r<4;r++){ v[r] += __shfl_xor(v[r], s, 64); }
  }
  if (lane==0){
    #pragma unroll
    for (int r=0;r<4;r++) wred[wid*4+r]=v[r];
  }
  __syncthreads();
  #pragma unroll
  for (int r=0;r<4;r++)
    v[r] = (wred[0*4+r]+wred[1*4+r]) + (wred[2*4+r]+wred[3*4+r]);
  __syncthreads();
}

// K1: threefry2x32-20 gumbel noise + c0 = relu(b1)@W2 + b2
__global__ void gumbel_kernel(float* g, float* c0, const float* w_b1,
                              const float* w_W2, const float* w_b2){
  int j = blockIdx.x*blockDim.x + threadIdx.x;
  if (j < 4096) {
    const unsigned k0=0u, k1=42u;
    const unsigned ks2 = k0^k1^0x1BD11BDAu;
    unsigned x0 = (unsigned)j, x1 = (unsigned)j + 4096u;
    const int r0[4]={13,15,26,6}, r1[4]={17,29,16,24};
    x0 += k0; x1 += k1;
    #pragma unroll
    for(int i=0;i<4;i++){ x0+=x1; x1=rotl32(x1,r0[i]); x1^=x0; }
    x0+=k1; x1+=ks2+1u;
    #pragma unroll
    for(int i=0;i<4;i++){ x0+=x1; x1=rotl32(x1,r1[i]); x1^=x0; }
    x0+=ks2; x1+=k0+2u;
    #pragma unroll
    for(int i=0;i<4;i++){ x0+=x1; x1=rotl32(x1,r0[i]); x1^=x0; }
    x0+=k0; x1+=k1+3u;
    #pragma unroll
    for(int i=0;i<4;i++){ x0+=x1; x1=rotl32(x1,r1[i]); x1^=x0; }
    x0+=k1; x1+=ks2+4u;
    #pragma unroll
    for(int i=0;i<4;i++){ x0+=x1; x1=rotl32(x1,r0[i]); x1^=x0; }
    x0+=ks2; x1+=k0+5u;
    g[j]        = bits_to_gumbel(x0);
    g[j+4096]   = bits_to_gumbel(x1);
  }
  if (blockIdx.x==0 && threadIdx.x==0){
    float s = 0.f;
    for (int h=0;h<HDIM;h++) s += fmaxf(w_b1[h],0.f)*w_W2[h];
    c0[0] = s + w_b2[0];
  }
}

// K2: ef_init = H@af ; edge_type = H@at  (compact-then-stream)
__global__ void incidence_kernel(const float* Hm, const float* af, const float* at,
                                 float* ef0, float* etype){
  __shared__ int ecomp[NN];
  __shared__ int wcnt[2];
  int be = blockIdx.x;
  int d  = threadIdx.x;           // 128 (2 waves)
  int b  = be / EE;
  int lane = d & 63, wid = d >> 6;
  const float* Hrow = Hm + (size_t)be*NN;
  int total = 0;
  #pragma unroll
  for (int p=0;p<2;p++){
    int n = p*128 + d;
    bool pred = (Hrow[n] != 0.f);
    unsigned long long mask = __ballot(pred);
    if (lane==0) wcnt[wid] = __popcll(mask);
    int off = __popcll(mask & ((1ull<<lane)-1ull));
    __syncthreads();
    int wb = total + (wid==1 ? wcnt[0] : 0);
    if (pred) ecomp[wb+off] = n;
    total += wcnt[0]+wcnt[1];
    __syncthreads();
  }
  float acc = 0.f, acct = 0.f;
  for (int i=0;i<total;i++){
    int n = ecomp[i];
    acc += af[((size_t)b*NN+n)*DD + d];
    if (d < TT) acct += at[((size_t)b*NN+n)*TT + d];
  }
  ef0[(size_t)be*DD+d] = acc;
  if (d < TT) etype[(size_t)be*TT+d] = acct;
}

// K3: merged U1 (1024 rows, blocks 0..255) + V (512 rows, blocks 256..383)
// R=4, float4 weights, 4-way k-split
__global__ void uv_mlp_kernel(const float* ef0, const float* afm, const float* wW1,
                              const float* wb1, float* U1, float* Vout){
  __shared__ float xs[4][DD];
  __shared__ float part[4*4*HDIM];   // 16KB
  int t = threadIdx.x;               // 256
  const float* src; const float* W; const float* bias; float* dst; int r0;
  if (blockIdx.x < 256){ src=ef0; W=wW1; bias=wb1; dst=U1; r0=blockIdx.x*4; }
  else { src=afm; W=wW1 + (size_t)DD*HDIM; bias=nullptr; dst=Vout; r0=(blockIdx.x-256)*4; }
  for (int i=t;i<4*DD;i+=256) xs[i>>7][i&127] = src[(size_t)(r0+(i>>7))*DD + (i&127)];
  __syncthreads();
  int c = (t&63)*4, ks = t>>6;
  float4 acc[4];
  #pragma unroll
  for (int r=0;r<4;r++) acc[r]=make_float4(0.f,0.f,0.f,0.f);
  #pragma unroll 8
  for (int i=ks*32; i<ks*32+32; i++){
    float4 w = *(const float4*)&W[(size_t)i*HDIM + c];
    #pragma unroll
    for (int r=0;r<4;r++) f4fma(acc[r], xs[r][i], w);
  }
  #pragma unroll
  for (int r=0;r<4;r++) *(float4*)&part[(ks*4+r)*HDIM + c] = acc[r];
  __syncthreads();
  float bv = bias ? bias[t] : 0.f;
  #pragma unroll
  for (int r=0;r<4;r++){
    float s = (part[(0*4+r)*HDIM+t] + part[(1*4+r)*HDIM+t])
            + (part[(2*4+r)*HDIM+t] + part[(3*4+r)*HDIM+t]);
    dst[(size_t)(r0+r)*HDIM + t] = s + bv;
  }
}

// standalone R=4 row-MLP (for U2 = ete@W1[:D]+b1), same structure
__global__ void rowmlp4_kernel(const float* src, const float* W, const float* bias, float* dst){
  __shared__ float xs[4][DD];
  __shared__ float part[4*4*HDIM];
  int t = threadIdx.x;
  int r0 = blockIdx.x*4;
  for (int i=t;i<4*DD;i+=256) xs[i>>7][i&127] = src[(size_t)(r0+(i>>7))*DD + (i&127)];
  __syncthreads();
  int c = (t&63)*4, ks = t>>6;
  float4 acc[4];
  #pragma unroll
  for (int r=0;r<4;r++) acc[r]=make_float4(0.f,0.f,0.f,0.f);
  #pragma unroll 8
  for (int i=ks*32; i<ks*32+32; i++){
    float4 w = *(const float4*)&W[(size_t)i*HDIM + c];
    #pragma unroll
    for (int r=0;r<4;r++) f4fma(acc[r], xs[r][i], w);
  }
  #pragma unroll
  for (int r=0;r<4;r++) *(float4*)&part[(ks*4+r)*HDIM + c] = acc[r];
  __syncthreads();
  float bv = bias ? bias[t] : 0.f;
  #pragma unroll
  for (int r=0;r<4;r++){
    float s = (part[(0*4+r)*HDIM+t] + part[(1*4+r)*HDIM+t])
            + (part[(2*4+r)*HDIM+t] + part[(3*4+r)*HDIM+t]);
    dst[(size_t)(r0+r)*HDIM + t] = s + bv;
  }
}

// K4: level-1 relu-dot + masked softmax, R=4 edges/block
__global__ void ew_softmax4_kernel(const float* U1, const float* Vm, const float* Hm,
                                   const float* w_W2, const float* w_b2, float* Hw){
  __shared__ float u[4][HDIM];
  __shared__ float w2[HDIM];
  __shared__ float wred[16];
  int e0 = blockIdx.x*4;
  int b = e0 >> 9;                 // /EE
  int n = threadIdx.x;             // 256
  for (int i=n;i<4*HDIM;i+=256) u[i>>8][i&255] = U1[(size_t)(e0+(i>>8))*HDIM + (i&255)];
  w2[n] = w_W2[n];
  __syncthreads();
  const float4* Vrow = (const float4*)(Vm + ((size_t)(b*NN)+n)*HDIM);
  float acc[4]={0.f,0.f,0.f,0.f};
  #pragma unroll 4
  for (int ii=0;ii<HDIM/4;ii++){
    float4 v = Vrow[ii];
    float w0=w2[4*ii+0], w1=w2[4*ii+1], wc=w2[4*ii+2], w3=w2[4*ii+3];
    #pragma unroll
    for (int r=0;r<4;r++){
      acc[r] += fmaxf(u[r][4*ii+0]+v.x,0.f)*w0
              + fmaxf(u[r][4*ii+1]+v.y,0.f)*w1
              + fmaxf(u[r][4*ii+2]+v.z,0.f)*wc
              + fmaxf(u[r][4*ii+3]+v.w,0.f)*w3;
    }
  }
  float b2v = w_b2[0];
  float x[4], hv[4];
  #pragma unroll
  for (int r=0;r<4;r++){
    hv[r] = Hm[(size_t)(e0+r)*NN + n];
    x[r] = (hv[r]!=0.f) ? (acc[r]+b2v) : 0.f;
  }
  float m4[4]={x[0],x[1],x[2],x[3]};
  block_reduce4_max(m4, wred);
  float p4[4];
  #pragma unroll
  for (int r=0;r<4;r++) p4[r]=expf(x[r]-m4[r]);
  float s4[4]={p4[0],p4[1],p4[2],p4[3]};
  block_reduce4_sum(s4, wred);
  #pragma unroll
  for (int r=0;r<4;r++)
    Hw[(size_t)(e0+r)*NN + n] = (hv[r]!=0.f) ? p4[r]/s4[r] : 0.f;
}

// K5: edge_features = Hw@af (compact-then-stream)
__global__ void aggregate_kernel(const float* Wgt, const float* af, float* outp){
  __shared__ int   ecomp[NN];
  __shared__ float wcomp[NN];
  __shared__ int wcnt[2];
  int be = blockIdx.x; int d = threadIdx.x; int b = be/EE;   // 128 threads
  int lane = d & 63, wid = d >> 6;
  const float* wrow = Wgt + (size_t)be*NN;
  int total = 0;
  #pragma unroll
  for (int p=0;p<2;p++){
    int n = p*128 + d;
    float w = wrow[n];
    bool pred = (w != 0.f);
    unsigned long long mask = __ballot(pred);
    if (lane==0) wcnt[wid] = __popcll(mask);
    int off = __popcll(mask & ((1ull<<lane)-1ull));
    __syncthreads();
    int wb = total + (wid==1 ? wcnt[0] : 0);
    if (pred){ ecomp[wb+off] = n; wcomp[wb+off] = w; }
    total += wcnt[0]+wcnt[1];
    __syncthreads();
  }
  float acc = 0.f;
  for (int i=0;i<total;i++){
    acc += wcomp[i]*af[((size_t)b*NN+ecomp[i])*DD + d];
  }
  outp[(size_t)be*DD + d] = acc;
}

// K6: typed edge embedding, R=4 edges/block, float4 + 4-way k-split front MLPs
__global__ void type4_kernel(const float* edgef, const float* etype, const float* g,
                             const float* dW1, const float* db1, const float* dW2, const float* db2,
                             const float* fW1, const float* fb1, const float* fW2, const float* fb2,
                             const float* type_emb, float* ete){
  __shared__ float et[4][DD+TT];
  __shared__ float hd[4][HDIM];
  __shared__ float part[4*4*HDIM];     // 16KB
  __shared__ float redsm[256];
  __shared__ float w2s[HDIM*KK];       // 8KB
  __shared__ float wred[16];
  __shared__ float facs[4];
  __shared__ float zz[4][KK];
  __shared__ float pzs[4][KK];
  __shared__ float fdv[4][KK];
  int e0 = blockIdx.x*4; int t = threadIdx.x;   // 256
  for (int i=t;i<4*(DD+TT);i+=256){
    int r=i/(DD+TT), cc=i%(DD+TT);
    et[r][cc] = (cc<DD) ? edgef[(size_t)(e0+r)*DD+cc] : etype[(size_t)(e0+r)*TT + (cc-DD)];
  }
  for (int i=t;i<HDIM*KK;i+=256) w2s[i] = dW2[i];
  __syncthreads();
  int c=(t&63)*4, ks=t>>6;
  float4 ad4[4], af4[4];
  #pragma unroll
  for (int r=0;r<4;r++){ ad4[r]=make_float4(0.f,0.f,0.f,0.f); af4[r]=make_float4(0.f,0.f,0.f,0.f); }
  #pragma unroll 4
  for (int i=ks*34;i<ks*34+34;i++){
    float4 wd = *(const float4*)&dW1[(size_t)i*HDIM+c];
    float4 wf = *(const float4*)&fW1[(size_t)i*HDIM+c];
    #pragma unroll
    for (int r=0;r<4;r++){ float x=et[r][i]; f4fma(ad4[r],x,wd); f4fma(af4[r],x,wf); }
  }
  #pragma unroll
  for (int r=0;r<4;r++) *(float4*)&part[(ks*4+r)*HDIM+c]=ad4[r];
  __syncthreads();
  float bd = db1[t];
  #pragma unroll
  for (int r=0;r<4;r++){
    float s = (part[(0*4+r)*HDIM+t]+part[(1*4+r)*HDIM+t])
            + (part[(2*4+r)*HDIM+t]+part[(3*4+r)*HDIM+t]);
    hd[r][t] = fmaxf(s+bd, 0.f);
  }
  __syncthreads();
  #pragma unroll
  for (int r=0;r<4;r++) *(float4*)&part[(ks*4+r)*HDIM+c]=af4[r];
  __syncthreads();
  float bf = fb1[t], fw = fW2[t];
  float v4[4];
  #pragma unroll
  for (int r=0;r<4;r++){
    float s = (part[(0*4+r)*HDIM+t]+part[(1*4+r)*HDIM+t])
            + (part[(2*4+r)*HDIM+t]+part[(3*4+r)*HDIM+t]);
    v4[r] = fmaxf(s+bf,0.f)*fw;
  }
  block_reduce4_sum(v4, wred);
  if (t<4) facs[t] = 1.f/(1.f+expf(-(v4[t]+fb2[0])));
  // logits: t -> (r=t>>6, k=(t>>3)&7, j=t&7), partial over 32 h
  int rr_ = t>>6, kk_ = (t>>3)&7, jj_ = t&7;
  float lp = 0.f;
  #pragma unroll 4
  for (int h=jj_*32; h<jj_*32+32; h++) lp += hd[rr_][h]*w2s[h*KK + kk_];
  redsm[t] = lp;
  __syncthreads();
  if (t < 32){
    int r = t>>3, k = t&7;
    float s = db2[k] + g[(size_t)(e0+r)*KK + k];
    #pragma unroll
    for (int j=0;j<8;j++) s += redsm[(r<<6)|(k<<3)|j];
    zz[r][k] = s*2.0f;               // /tau, tau=0.5
  }
  __syncthreads();
  if (t < 32){
    int r = t>>3, k = t&7;
    float m = zz[r][0];
    #pragma unroll
    for (int k2=1;k2<KK;k2++) m = fmaxf(m, zz[r][k2]);
    pzs[r][k] = expf(zz[r][k]-m);
  }
  __syncthreads();
  if (t < 32){
    int r = t>>3, k = t&7;
    float s = 0.f;
    #pragma unroll
    for (int k2=0;k2<KK;k2++) s += pzs[r][k2];
    fdv[r][k] = facs[r]*pzs[r][k]/s;
  }
  __syncthreads();
  int d = t&127;
  #pragma unroll
  for (int rr=0;rr<2;rr++){
    int r = 2*rr + (t>>7);
    float acc = 0.f;
    #pragma unroll
    for (int k=0;k<KK;k++) acc += fdv[r][k]*type_emb[(size_t)k*DD + d];
    ete[(size_t)(e0+r)*DD + d] = acc;
  }
}

// K8: level-2 relu-dot + leaky + full softmax, R=4; writes TRANSPOSED Hw2T[b][n][e]
__global__ void hw2_softmax4_kernel(const float* U2, const float* Vm, const float* Hm,
                                    const float* w_W2, const float* w_b2, const float* c0p,
                                    float* HwT){
  __shared__ float u[4][HDIM];
  __shared__ float w2[HDIM];
  __shared__ float wred[16];
  int e0 = blockIdx.x*4;
  int b = e0 >> 9;
  int n = threadIdx.x;
  for (int i=n;i<4*HDIM;i+=256) u[i>>8][i&255] = U2[(size_t)(e0+(i>>8))*HDIM + (i&255)];
  w2[n] = w_W2[n];
  __syncthreads();
  const float4* Vrow = (const float4*)(Vm + ((size_t)(b*NN)+n)*HDIM);
  float acc[4]={0.f,0.f,0.f,0.f};
  #pragma unroll 4
  for (int ii=0;ii<HDIM/4;ii++){
    float4 v = Vrow[ii];
    float w0=w2[4*ii+0], w1=w2[4*ii+1], wc=w2[4*ii+2], w3=w2[4*ii+3];
    #pragma unroll
    for (int r=0;r<4;r++){
      acc[r] += fmaxf(u[r][4*ii+0]+v.x,0.f)*w0
              + fmaxf(u[r][4*ii+1]+v.y,0.f)*w1
              + fmaxf(u[r][4*ii+2]+v.z,0.f)*wc
              + fmaxf(u[r][4*ii+3]+v.w,0.f)*w3;
    }
  }
  float b2v = w_b2[0];
  float c0 = c0p[0];
  float x[4], hv[4];
  #pragma unroll
  for (int r=0;r<4;r++){
    hv[r] = Hm[(size_t)(e0+r)*NN + n];
    float raw = (hv[r]!=0.f) ? (acc[r]+b2v) : c0;
    x[r] = raw>0.f ? raw : 0.01f*raw;        // leaky relu
  }
  float m4[4]={x[0],x[1],x[2],x[3]};
  block_reduce4_max(m4, wred);
  float p4[4];
  #pragma unroll
  for (int r=0;r<4;r++) p4[r]=expf(x[r]-m4[r]);
  float s4[4]={p4[0],p4[1],p4[2],p4[3]};
  block_reduce4_sum(s4, wred);
  int eb = e0 & 511;                         // local e within batch
  float4 o4;
  o4.x = (hv[0]!=0.f)? p4[0]/s4[0] : 0.f;
  o4.y = (hv[1]!=0.f)? p4[1]/s4[1] : 0.f;
  o4.z = (hv[2]!=0.f)? p4[2]/s4[2] : 0.f;
  o4.w = (hv[3]!=0.f)? p4[3]/s4[3] : 0.f;
  *(float4*)(HwT + ((size_t)(b*NN)+n)*EE + eb) = o4;
}

// K9: msg via transposed Hw2T (coalesced scan) + compaction
__global__ void msg_kernel(const float* HwT, const float* edgef, const float* ete,
                           const float* af, float* agf){
  __shared__ int   ecomp[EE];
  __shared__ float wcomp[EE];
  __shared__ int wcnt[4];
  int bn = blockIdx.x; int b = bn>>8; int f = threadIdx.x; // 256 (4 waves)
  int lane = f & 63, wid = f >> 6;
  const float* wrow = HwT + (size_t)bn*EE;
  int total = 0;
  #pragma unroll
  for (int p=0;p<2;p++){
    int e = p*256 + f;
    float w = wrow[e];
    bool pred = (w != 0.f);
    unsigned long long mask = __ballot(pred);
    if (lane==0) wcnt[wid] = __popcll(mask);
    int off = __popcll(mask & ((1ull<<lane)-1ull));
    __syncthreads();
    int wb = total;
    for (int ww=0; ww<wid; ww++) wb += wcnt[ww];
    if (pred){ ecomp[wb+off] = e; wcomp[wb+off] = w; }
    total += wcnt[0]+wcnt[1]+wcnt[2]+wcnt[3];
    __syncthreads();
  }
  float acc = 0.f;
  const float* srcbase = (f < DD) ? (edgef + (size_t)b*EE*DD + f)
                                  : (ete   + (size_t)b*EE*DD + (f-DD));
  for (int i=0;i<total;i++){
    acc += wcomp[i] * srcbase[(size_t)ecomp[i]*DD];
  }
  agf[(size_t)bn*(3*DD)+f] = acc;
  if (f < DD) agf[(size_t)bn*(3*DD) + 2*DD + f] = af[(size_t)bn*DD + f];
}

// ---- shared helper: 4 rows x (128->128) dense layer, float4 + 8-way k-split ----
__device__ __forceinline__ void mlp128_lds(const float (*in)[DD], const float* W, const float* bias,
                                           float (*outl)[DD], float* part, int t){
  int c=(t&31)*4, ks=t>>5;
  float4 a[4];
  #pragma unroll
  for (int r=0;r<4;r++) a[r]=make_float4(0.f,0.f,0.f,0.f);
  #pragma unroll 4
  for (int i=ks*16;i<ks*16+16;i++){
    float4 w = *(const float4*)&W[(size_t)i*DD+c];
    #pragma unroll
    for (int r=0;r<4;r++) f4fma(a[r], in[r][i], w);
  }
  #pragma unroll
  for (int r=0;r<4;r++) *(float4*)&part[(ks*4+r)*DD+c]=a[r];
  __syncthreads();
  int cc=t&127, rh=t>>7;
  for (int rr=rh; rr<4; rr+=2){
    float s=0.f;
    #pragma unroll
    for (int k2=0;k2<8;k2++) s+=part[(k2*4+rr)*DD+cc];
    outl[rr][cc]=s+bias[cc];
  }
  __syncthreads();
}

__device__ __forceinline__ void mlp128_glob(const float (*in)[DD], const float* W, const float* bias,
                                            float* dst, int r0, float* part, int t){
  int c=(t&31)*4, ks=t>>5;
  float4 a[4];
  #pragma unroll
  for (int r=0;r<4;r++) a[r]=make_float4(0.f,0.f,0.f,0.f);
  #pragma unroll 4
  for (int i=ks*16;i<ks*16+16;i++){
    float4 w = *(const float4*)&W[(size_t)i*DD+c];
    #pragma unroll
    for (int r=0;r<4;r++) f4fma(a[r], in[r][i], w);
  }
  #pragma unroll
  for (int r=0;r<4;r++) *(float4*)&part[(ks*4+r)*DD+c]=a[r];
  __syncthreads();
  int cc=t&127, rh=t>>7;
  for (int rr=rh; rr<4; rr+=2){
    float s=0.f;
    #pragma unroll
    for (int k2=0;k2<8;k2++) s+=part[(k2*4+rr)*DD+cc];
    dst[(size_t)(r0+rr)*DD+cc]=s+bias[cc];
  }
  __syncthreads();
}

// K10: merged q2 (blocks 0..127) and k2/v2 (blocks 128..255), R=4
__global__ void q2kv_kernel(const float* agf, const float* qW, const float* qb,
                            const float* iqW, const float* iqb,
                            const float* pf,
                            const float* kW, const float* kb, const float* ikW, const float* ikb,
                            const float* vW, const float* vb, const float* ivW, const float* ivb,
                            float* q2, float* k2, float* v2){
  __shared__ float xs[4][3*DD];     // 6KB
  __shared__ float bufA[4][DD];     // 2KB
  __shared__ float bufB[4][DD];     // 2KB
  __shared__ float part[8*4*DD];    // 16KB
  int t = threadIdx.x;              // 256
  if (blockIdx.x < 128){
    int r0 = blockIdx.x*4;
    #pragma unroll
    for (int r=0;r<4;r++)
      for (int cc=t;cc<3*DD;cc+=256) xs[r][cc] = agf[(size_t)(r0+r)*(3*DD)+cc];
    __syncthreads();
    // stage A: (4 x 384) @ (384 x 128), 8-way k-split, slice 48
    int c=(t&31)*4, ks=t>>5;
    float4 a[4];
    #pragma unroll
    for (int r=0;r<4;r++) a[r]=make_float4(0.f,0.f,0.f,0.f);
    #pragma unroll 4
    for (int i=ks*48;i<ks*48+48;i++){
      float4 w = *(const float4*)&qW[(size_t)i*DD+c];
      #pragma unroll
      for (int r=0;r<4;r++) f4fma(a[r], xs[r][i], w);
    }
    #pragma unroll
    for (int r=0;r<4;r++) *(float4*)&part[(ks*4+r)*DD+c]=a[r];
    __syncthreads();
    int cc=t&127, rh=t>>7;
    for (int rr=rh; rr<4; rr+=2){
      float s=0.f;
      #pragma unroll
      for (int k2_=0;k2_<8;k2_++) s+=part[(k2_*4+rr)*DD+cc];
      bufA[rr][cc]=s+qb[cc];
    }
    __syncthreads();
    mlp128_glob(bufA, iqW, iqb, q2, r0, part, t);
  } else {
    int r0 = (blockIdx.x-128)*4;
    for (int i=t;i<4*DD;i+=256) bufA[i>>7][i&127] = pf[(size_t)(r0+(i>>7))*DD + (i&127)];
    __syncthreads();
    mlp128_lds (bufA, kW, kb, bufB, part, t);
    mlp128_glob(bufB, ikW, ikb, k2, r0, part, t);
    mlp128_lds (bufA, vW, vb, bufB, part, t);
    mlp128_glob(bufB, ivW, ivb, v2, r0, part, t);
  }
}

// K10c: 4-head cross attention + out-proj, R=2 q-rows/block, 256 blocks
__global__ void attn2_kernel(const float* q2, const float* k2, const float* v2,
                             const float* op_W, const float* op_b, float* pnew){
  __shared__ float qr[2][DD];
  __shared__ float att[2][4][PP+1];   // pad kills bank conflict on broadcast
  __shared__ float o_l[2][DD];
  __shared__ float part[8*2*DD];      // 8KB
  int r0 = blockIdx.x*2; int b = r0 >> 8; int t = threadIdx.x; // 256, t = p index
  for (int i=t;i<2*DD;i+=256) qr[i>>7][i&127] = q2[(size_t)(r0+(i>>7))*DD + (i&127)];
  __syncthreads();
  const float scale = 0.17677669529663687f;  // 1/sqrt(32)
  const float* krow = k2 + ((size_t)(b*PP) + t)*DD;
  #pragma unroll
  for (int h=0;h<4;h++){
    const float4* k4 = (const float4*)(krow + h*32);
    float s[2]={0.f,0.f};
    #pragma unroll
    for (int jj=0;jj<8;jj++){
      float4 kk = k4[jj];
      #pragma unroll
      for (int r=0;r<2;r++){
        s[r] += qr[r][h*32+jj*4+0]*kk.x + qr[r][h*32+jj*4+1]*kk.y
              + qr[r][h*32+jj*4+2]*kk.z + qr[r][h*32+jj*4+3]*kk.w;
      }
    }
    #pragma unroll
    for (int r=0;r<2;r++) att[r][h][t] = s[r]*scale;
  }
  __syncthreads();
  {
    int lane = t & 63, wid = t >> 6;
    for (int q = wid; q < 8; q += 4){
      int r = q >> 2, h = q & 3;
      float v0 = att[r][h][lane],     v1 = att[r][h][lane+64],
            ve = att[r][h][lane+128], v3 = att[r][h][lane+192];
      float m = fmaxf(fmaxf(v0,v1), fmaxf(ve,v3));
      #pragma unroll
      for (int s2=32;s2>0;s2>>=1) m = fmaxf(m, __shfl_xor(m, s2, 64));
      float e0 = expf(v0-m), e1 = expf(v1-m), e2 = expf(ve-m), e3 = expf(v3-m);
      float ss = (e0+e1)+(e2+e3);
      #pragma unroll
      for (int s2=32;s2>0;s2>>=1) ss += __shfl_xor(ss, s2, 64);
      float inv = 1.f/ss;
      att[r][h][lane] = e0*inv; att[r][h][lane+64] = e1*inv;
      att[r][h][lane+128] = e2*inv; att[r][h][lane+192] = e3*inv;
    }
  }
  __syncthreads();
  // PV: float4 over cols, 8-way p-split
  int c=(t&31)*4, ps=t>>5; int h2 = c>>5;
  {
    float4 acc[2];
    #pragma unroll
    for (int r=0;r<2;r++) acc[r]=make_float4(0.f,0.f,0.f,0.f);
    #pragma unroll 4
    for (int i=0;i<32;i++){
      int p = ps*32+i;
      float4 v = *(const float4*)&v2[((size_t)(b*PP)+p)*DD + c];
      #pragma unroll
      for (int r=0;r<2;r++) f4fma(acc[r], att[r][h2][p], v);
    }
    #pragma unroll
    for (int r=0;r<2;r++) *(float4*)&part[(ps*2+r)*DD+c]=acc[r];
  }
  __syncthreads();
  {
    int cc=t&127, r=t>>7;
    float s=0.f;
    #pragma unroll
    for (int k2_=0;k2_<8;k2_++) s+=part[(k2_*2+r)*DD+cc];
    o_l[r][cc]=s;
  }
  __syncthreads();
  // out-proj: (2 x 128) @ (128 x 128), 8-way k-split, slice 16
  {
    float4 a2[2];
    #pragma unroll
    for (int r=0;r<2;r++) a2[r]=make_float4(0.f,0.f,0.f,0.f);
    #pragma unroll 4
    for (int i=ps*16;i<ps*16+16;i++){
      float4 w = *(const float4*)&op_W[(size_t)i*DD + c];
      #pragma unroll
      for (int r=0;r<2;r++) f4fma(a2[r], o_l[r][i], w);
    }
    #pragma unroll
    for (int r=0;r<2;r++) *(float4*)&part[(ps*2+r)*DD+c]=a2[r];
  }
  __syncthreads();
  {
    int cc=t&127, r=t>>7;
    float s=0.f;
    #pragma unroll
    for (int k2_=0;k2_<8;k2_++) s+=part[(k2_*2+r)*DD+cc];
    pnew[(size_t)(r0+r)*DD+cc]=s+op_b[cc];
  }
}

// K11: agent_new = MLP([agf, pnew]), R=2 rows/block, 256 blocks, float4 + k-split
__global__ void final2_kernel(const float* agf, const float* pnewv,
                              const float* oW1, const float* ob1,
                              const float* oW2, const float* ob2, float* anew){
  __shared__ float xs[2][4*DD];      // 4KB
  __shared__ float hid[2][HDIM];     // 2KB
  __shared__ float part[4*2*HDIM];   // 8KB (stage2 reuses as [8][2][128])
  int r0 = blockIdx.x*2; int t = threadIdx.x;   // 256
  for (int i=t;i<2*(4*DD);i+=256){
    int r = i>>9, cc = i&511;
    xs[r][cc] = (cc<3*DD) ? agf[(size_t)(r0+r)*(3*DD)+cc]
                          : pnewv[(size_t)(r0+r)*DD + (cc-3*DD)];
  }
  __syncthreads();
  // stage1: (2 x 512) @ (512 x 256), KS=4, slice 128
  {
    int c=(t&63)*4, ks=t>>6;
    float4 acc[2];
    #pragma unroll
    for (int r=0;r<2;r++) acc[r]=make_float4(0.f,0.f,0.f,0.f);
    #pragma unroll 8
    for (int i=ks*128;i<ks*128+128;i++){
      float4 w = *(const float4*)&oW1[(size_t)i*HDIM+c];
      #pragma unroll
      for (int r=0;r<2;r++) f4fma(acc[r], xs[r][i], w);
    }
    #pragma unroll
    for (int r=0;r<2;r++) *(float4*)&part[(ks*2+r)*HDIM+c]=acc[r];
  }
  __syncthreads();
  {
    float bv = ob1[t];
    #pragma unroll
    for (int r=0;r<2;r++){
      float s = (part[(0*2+r)*HDIM+t]+part[(1*2+r)*HDIM+t])
              + (part[(2*2+r)*HDIM+t]+part[(3*2+r)*HDIM+t]);
      hid[r][t] = fmaxf(s+bv, 0.f);
    }
  }
  __syncthreads();
  // stage2: (2 x 256) @ (256 x 128), KS=8, slice 32
  {
    int c2=(t&31)*4, ks2=t>>5;
    float4 a2[2];
    #pragma unroll
    for (int r=0;r<2;r++) a2[r]=make_float4(0.f,0.f,0.f,0.f);
    #pragma unroll 8
    for (int h=ks2*32;h<ks2*32+32;h++){
      float4 w = *(const float4*)&oW2[(size_t)h*DD+c2];
      #pragma unroll
      for (int r=0;r<2;r++) f4fma(a2[r], hid[r][h], w);
    }
    #pragma unroll
    for (int r=0;r<2;r++) *(float4*)&part[(ks2*2+r)*DD+c2]=a2[r];
  }
  __syncthreads();
  {
    int cc=t&127, r=t>>7;
    float s=0.f;
    #pragma unroll
    for (int k2_=0;k2_<8;k2_++) s+=part[(k2_*2+r)*DD+cc];
    anew[(size_t)(r0+r)*DD+cc]=s+ob2[cc];
  }
}

extern "C" void kernel_launch(void* const* d_in, const int* in_sizes, int n_in,
                              void* d_out, int out_size, void* d_ws, size_t ws_size,
                              hipStream_t stream) {
  const float* af       = (const float*)d_in[0];
  const float* at       = (const float*)d_in[1];
  const float* pf       = (const float*)d_in[2];
  const float* Hm       = (const float*)d_in[3];
  const float* type_emb = (const float*)d_in[4];
  const float* w_W1 = (const float*)d_in[5];
  const float* w_b1 = (const float*)d_in[6];
  const float* w_W2 = (const float*)d_in[7];
  const float* w_b2 = (const float*)d_in[8];
  const float* d_W1 = (const float*)d_in[9];
  const float* d_b1 = (const float*)d_in[10];
  const float* d_W2 = (const float*)d_in[11];
  const float* d_b2 = (const float*)d_in[12];
  const float* f_W1 = (const float*)d_in[13];
  const float* f_b1 = (const float*)d_in[14];
  const float* f_W2 = (const float*)d_in[15];
  const float* f_b2 = (const float*)d_in[16];
  const float* o_W1 = (const float*)d_in[17];
  const float* o_b1 = (const float*)d_in[18];
  const float* o_W2 = (const float*)d_in[19];
  const float* o_b2 = (const float*)d_in[20];
  const float* q_W  = (const float*)d_in[21];
  const float* q_b  = (const float*)d_in[22];
  const float* k_W  = (const float*)d_in[23];
  const float* k_b  = (const float*)d_in[24];
  const float* v_W  = (const float*)d_in[25];
  const float* v_b  = (const float*)d_in[26];
  const float* iq_W = (const float*)d_in[27];
  const float* iq_b = (const float*)d_in[28];
  const float* ik_W = (const float*)d_in[29];
  const float* ik_b = (const float*)d_in[30];
  const float* iv_W = (const float*)d_in[31];
  const float* iv_b = (const float*)d_in[32];
  const float* op_W = (const float*)d_in[33];
  const float* op_b = (const float*)d_in[34];

  float* ws   = (float*)d_ws;
  float* out  = (float*)d_out;
  float* anew = out;                 // (B,N,D)
  float* pnew = out + BB*NN*DD;      // (B,N,D)

  gumbel_kernel<<<16,256,0,stream>>>(ws+WS_G, ws+WS_C0, w_b1, w_W2, w_b2);
  incidence_kernel<<<BB*EE,128,0,stream>>>(Hm, af, at, ws+WS_EF0, ws+WS_ETYPE);
  uv_mlp_kernel<<<384,256,0,stream>>>(ws+WS_EF0, af, w_W1, w_b1, ws+WS_U1, ws+WS_V);
  ew_softmax4_kernel<<<256,256,0,stream>>>(ws+WS_U1, ws+WS_V, Hm, w_W2, w_b2, ws+WS_HW);
  aggregate_kernel<<<BB*EE,128,0,stream>>>(ws+WS_HW, af, ws+WS_EDGEF);
  type4_kernel<<<256,256,0,stream>>>(ws+WS_EDGEF, ws+WS_ETYPE, ws+WS_G,
                                     d_W1,d_b1,d_W2,d_b2, f_W1,f_b1,f_W2,f_b2,
                                     type_emb, ws+WS_EF0 /*ete*/);
  rowmlp4_kernel<<<256,256,0,stream>>>(ws+WS_EF0, w_W1, w_b1, ws+WS_U1 /*U2*/);
  hw2_softmax4_kernel<<<256,256,0,stream>>>(ws+WS_U1, ws+WS_V, Hm, w_W2, w_b2,
                                            ws+WS_C0, ws+WS_HWT);
  msg_kernel<<<BB*NN,256,0,stream>>>(ws+WS_HWT, ws+WS_EDGEF, ws+WS_EF0, af, ws+WS_AGF);
  q2kv_kernel<<<256,256,0,stream>>>(ws+WS_AGF, q_W,q_b,iq_W,iq_b, pf,
                                    k_W,k_b,ik_W,ik_b, v_W,v_b,iv_W,iv_b,
                                    ws+WS_Q2, ws+WS_K2, ws+WS_V2);
  attn2_kernel<<<256,256,0,stream>>>(ws+WS_Q2, ws+WS_K2, ws+WS_V2, op_W, op_b, pnew);
  final2_kernel<<<256,256,0,stream>>>(ws+WS_AGF, pnew, o_W1,o_b1,o_W2,o_b2, anew);
}

// Round 5
// 104.386 us; speedup vs baseline: 2.0346x; 1.2582x over previous
//
#include <hip/hip_runtime.h>
#include <math.h>

#define BB 2
#define NN 256
#define EE 512
#define PP 256
#define DD 128
#define TT 8
#define KK 8
#define HDIM 256

// workspace offsets (floats)
#define WS_G      0          // B*E*K = 8192
#define WS_C0     8192       // 64
#define WS_EF0    8256       // B*E*D = 131072
#define WS_ETYPE  139328     // B*E*T = 8192
#define WS_V      147520     // B*N*HD = 131072
#define WS_EDGEF  278592     // B*E*D = 131072
#define WS_ETE    409664     // B*E*D = 131072
#define WS_HWT    540736     // B*N*E = 262144 (transposed Hw2)
#define WS_AGF    802880     // B*N*3D = 196608
#define WS_Q2     999488     // 65536
#define WS_K2     1065024    // 65536
#define WS_V2     1130560    // 65536
// total 1196096 floats = 4.78 MB

__device__ inline unsigned rotl32(unsigned x, int d){ return (x<<d)|(x>>(32-d)); }

__device__ inline float bits_to_gumbel(unsigned bits){
  float f = __uint_as_float((bits>>9)|0x3f800000u) - 1.0f;
  const float minv = 1e-6f;
  const float maxv = 1.0f - 1e-6f;
  float u = f*(maxv-minv) + minv;
  u = fmaxf(minv, u);
  return -logf(-logf(u));
}

__device__ __forceinline__ void f4fma(float4& a, float x, const float4& w){
  a.x += x*w.x; a.y += x*w.y; a.z += x*w.z; a.w += x*w.w;
}

// ---- block-wide reduction of 4 values over 256 threads (4 waves) ----
__device__ __forceinline__ void block_reduce4_max(float v[4], float* wred){
  int lane = threadIdx.x & 63, wid = threadIdx.x >> 6;
  #pragma unroll
  for (int s=32;s>0;s>>=1){
    #pragma unroll
    for (int r=0;r<4;r++){ float o = __shfl_xor(v[r], s, 64); v[r] = fmaxf(v[r],o); }
  }
  if (lane==0){
    #pragma unroll
    for (int r=0;r<4;r++) wred[wid*4+r]=v[r];
  }
  __syncthreads();
  #pragma unroll
  for (int r=0;r<4;r++)
    v[r] = fmaxf(fmaxf(wred[0*4+r],wred[1*4+r]), fmaxf(wred[2*4+r],wred[3*4+r]));
  __syncthreads();
}

__device__ __forceinline__ void block_reduce4_sum(float v[4], float* wred){
  int lane = threadIdx.x & 63, wid = threadIdx.x >> 6;
  #pragma unroll
  for (int s=32;s>0;s>>=1){
    #pragma unroll
    for (int r=0;r<4;r++){ v[r] += __shfl_xor(v[r], s, 64); }
  }
  if (lane==0){
    #pragma unroll
    for (int r=0;r<4;r++) wred[wid*4+r]=v[r];
  }
  __syncthreads();
  #pragma unroll
  for (int r=0;r<4;r++)
    v[r] = (wred[0*4+r]+wred[1*4+r]) + (wred[2*4+r]+wred[3*4+r]);
  __syncthreads();
}

// =========================================================================
// K1 prep: gumbel noise (blocks 0..15) + c0 (block 0) + incidence (16..1039)
//          + V row-MLP (1040..1167)
// =========================================================================
__global__ void prep_kernel(float* g, float* c0, const float* w_b1,
                            const float* w_W2, const float* w_b2,
                            const float* Hm, const float* af, const float* at,
                            float* ef0, float* etype,
                            const float* wW1, float* Vout){
  __shared__ int   ecomp[NN];
  __shared__ int   wcnt[4];
  __shared__ float accl[2][DD];
  __shared__ float acctl[2][TT];
  __shared__ float xs[4][DD];
  __shared__ float part[4*4*HDIM];   // 16KB
  __shared__ float wred[16];
  int blk = blockIdx.x;
  int t = threadIdx.x;               // 256
  int lane = t & 63, wid = t >> 6;

  if (blk < 16){
    // ---- gumbel: j = blk*256 + t ----
    int j = blk*256 + t;
    {
      const unsigned k0=0u, k1=42u;
      const unsigned ks2 = k0^k1^0x1BD11BDAu;
      unsigned x0 = (unsigned)j, x1 = (unsigned)j + 4096u;
      const int r0[4]={13,15,26,6}, r1[4]={17,29,16,24};
      x0 += k0; x1 += k1;
      #pragma unroll
      for(int i=0;i<4;i++){ x0+=x1; x1=rotl32(x1,r0[i]); x1^=x0; }
      x0+=k1; x1+=ks2+1u;
      #pragma unroll
      for(int i=0;i<4;i++){ x0+=x1; x1=rotl32(x1,r1[i]); x1^=x0; }
      x0+=ks2; x1+=k0+2u;
      #pragma unroll
      for(int i=0;i<4;i++){ x0+=x1; x1=rotl32(x1,r0[i]); x1^=x0; }
      x0+=k0; x1+=k1+3u;
      #pragma unroll
      for(int i=0;i<4;i++){ x0+=x1; x1=rotl32(x1,r1[i]); x1^=x0; }
      x0+=k1; x1+=ks2+4u;
      #pragma unroll
      for(int i=0;i<4;i++){ x0+=x1; x1=rotl32(x1,r0[i]); x1^=x0; }
      x0+=ks2; x1+=k0+5u;
      g[j]      = bits_to_gumbel(x0);
      g[j+4096] = bits_to_gumbel(x1);
    }
    if (blk == 0){
      // c0 = relu(b1)@W2 + b2, block-parallel
      float v4[4];
      v4[0] = fmaxf(w_b1[t],0.f)*w_W2[t]; v4[1]=0.f; v4[2]=0.f; v4[3]=0.f;
      block_reduce4_sum(v4, wred);
      if (t==0) c0[0] = v4[0] + w_b2[0];
    }
  } else if (blk < 16+BB*EE){
    // ---- incidence: compact H row then stream ----
    int be = blk - 16;
    int b  = be / EE;
    const float* Hrow = Hm + (size_t)be*NN;
    int n = t;
    bool pred = (Hrow[n] != 0.f);
    unsigned long long mask = __ballot(pred);
    if (lane==0) wcnt[wid] = __popcll(mask);
    int off = __popcll(mask & ((1ull<<lane)-1ull));
    __syncthreads();
    int wb = 0;
    for (int ww=0; ww<wid; ww++) wb += wcnt[ww];
    if (pred) ecomp[wb+off] = n;
    int total = wcnt[0]+wcnt[1]+wcnt[2]+wcnt[3];
    __syncthreads();
    int d = t & 127, h2 = t >> 7;
    float acc = 0.f, acct = 0.f;
    for (int i=h2; i<total; i+=2){
      int n2 = ecomp[i];
      acc += af[((size_t)b*NN+n2)*DD + d];
      if (d < TT) acct += at[((size_t)b*NN+n2)*TT + d];
    }
    accl[h2][d] = acc;
    if (d < TT) acctl[h2][d] = acct;
    __syncthreads();
    if (t < DD) ef0[(size_t)be*DD + t] = accl[0][t] + accl[1][t];
    if (t < TT) etype[(size_t)be*TT + t] = acctl[0][t] + acctl[1][t];
  } else {
    // ---- V = af @ wW1[D:] (no bias), R=4 rows ----
    int r0 = (blk - (16+BB*EE))*4;
    const float* W = wW1 + (size_t)DD*HDIM;
    for (int i=t;i<4*DD;i+=256) xs[i>>7][i&127] = af[(size_t)(r0+(i>>7))*DD + (i&127)];
    __syncthreads();
    int c = (t&63)*4, ks = t>>6;
    float4 acc[4];
    #pragma unroll
    for (int r=0;r<4;r++) acc[r]=make_float4(0.f,0.f,0.f,0.f);
    #pragma unroll 8
    for (int i=ks*32; i<ks*32+32; i++){
      float4 w = *(const float4*)&W[(size_t)i*HDIM + c];
      #pragma unroll
      for (int r=0;r<4;r++) f4fma(acc[r], xs[r][i], w);
    }
    #pragma unroll
    for (int r=0;r<4;r++) *(float4*)&part[(ks*4+r)*HDIM + c] = acc[r];
    __syncthreads();
    #pragma unroll
    for (int r=0;r<4;r++){
      float s = (part[(0*4+r)*HDIM+t] + part[(1*4+r)*HDIM+t])
              + (part[(2*4+r)*HDIM+t] + part[(3*4+r)*HDIM+t]);
      Vout[(size_t)(r0+r)*HDIM + t] = s;
    }
  }
}

// =========================================================================
// K2 l1_fused: U1 = ef0@W1[:D]+b1 ; ew relu-dot ; masked softmax ;
//              aggregate edge_features = Hw@af  (Hw never leaves LDS)
// R=4 edges/block, 256 blocks
// =========================================================================
__global__ void l1_fused_kernel(const float* ef0, const float* Vm, const float* Hm,
                                const float* af, const float* wW1, const float* wb1,
                                const float* wW2, const float* wb2, float* edgef){
  __shared__ float xs[4][DD];         // 2KB
  __shared__ float part[4*4*HDIM];    // 16KB
  __shared__ float u[4][HDIM];        // 4KB
  __shared__ float w2l[HDIM];         // 1KB
  __shared__ float hwls[4][NN];       // 4KB
  __shared__ float wred[16];
  __shared__ int   ncomp[4][NN];      // 4KB
  __shared__ float ncw[4][NN];        // 4KB
  __shared__ int   ncnt[4];
  int e0 = blockIdx.x*4;
  int b  = e0 >> 9;
  int t  = threadIdx.x;               // 256
  int lane = t & 63, wid = t >> 6;

  // load ef0 rows + w2
  for (int i=t;i<4*DD;i+=256) xs[i>>7][i&127] = ef0[(size_t)(e0+(i>>7))*DD + (i&127)];
  w2l[t] = wW2[t];
  __syncthreads();
  // U1 (float4 + 4-way k-split)
  {
    int c = (t&63)*4, ks = t>>6;
    float4 acc[4];
    #pragma unroll
    for (int r=0;r<4;r++) acc[r]=make_float4(0.f,0.f,0.f,0.f);
    #pragma unroll 8
    for (int i=ks*32; i<ks*32+32; i++){
      float4 w = *(const float4*)&wW1[(size_t)i*HDIM + c];
      #pragma unroll
      for (int r=0;r<4;r++) f4fma(acc[r], xs[r][i], w);
    }
    #pragma unroll
    for (int r=0;r<4;r++) *(float4*)&part[(ks*4+r)*HDIM + c] = acc[r];
  }
  __syncthreads();
  {
    float bv = wb1[t];
    #pragma unroll
    for (int r=0;r<4;r++){
      float s = (part[(0*4+r)*HDIM+t] + part[(1*4+r)*HDIM+t])
              + (part[(2*4+r)*HDIM+t] + part[(3*4+r)*HDIM+t]);
      u[r][t] = s + bv;
    }
  }
  __syncthreads();
  // relu-dot over n = t
  int n = t;
  const float4* Vrow = (const float4*)(Vm + ((size_t)(b*NN)+n)*HDIM);
  float acc[4]={0.f,0.f,0.f,0.f};
  #pragma unroll 4
  for (int ii=0;ii<HDIM/4;ii++){
    float4 v = Vrow[ii];
    float w0=w2l[4*ii+0], w1=w2l[4*ii+1], wc=w2l[4*ii+2], w3=w2l[4*ii+3];
    #pragma unroll
    for (int r=0;r<4;r++){
      acc[r] += fmaxf(u[r][4*ii+0]+v.x,0.f)*w0
              + fmaxf(u[r][4*ii+1]+v.y,0.f)*w1
              + fmaxf(u[r][4*ii+2]+v.z,0.f)*wc
              + fmaxf(u[r][4*ii+3]+v.w,0.f)*w3;
    }
  }
  float b2v = wb2[0];
  float x[4], hv[4];
  #pragma unroll
  for (int r=0;r<4;r++){
    hv[r] = Hm[(size_t)(e0+r)*NN + n];
    x[r] = (hv[r]!=0.f) ? (acc[r]+b2v) : 0.f;
  }
  float m4[4]={x[0],x[1],x[2],x[3]};
  block_reduce4_max(m4, wred);
  float p4[4];
  #pragma unroll
  for (int r=0;r<4;r++) p4[r]=expf(x[r]-m4[r]);
  float s4[4]={p4[0],p4[1],p4[2],p4[3]};
  block_reduce4_sum(s4, wred);
  #pragma unroll
  for (int r=0;r<4;r++)
    hwls[r][n] = (hv[r]!=0.f) ? p4[r]/s4[r] : 0.f;
  __syncthreads();
  // per-wave compaction: wave wid owns edge r=wid
  {
    int r = wid;
    int base = 0;
    #pragma unroll
    for (int c4=0;c4<4;c4++){
      int n2 = c4*64 + lane;
      float w = hwls[r][n2];
      bool pred = (w != 0.f);
      unsigned long long mask = __ballot(pred);
      int off = __popcll(mask & ((1ull<<lane)-1ull));
      if (pred){ ncomp[r][base+off] = n2; ncw[r][base+off] = w; }
      base += __popcll(mask);
    }
    if (lane==0) ncnt[r] = base;
  }
  __syncthreads();
  // aggregate: thread (d, eh) handles 2 edges
  {
    int d = t & 127, eh = t >> 7;
    #pragma unroll
    for (int rr=0;rr<2;rr++){
      int r = eh*2 + rr;
      int tot = ncnt[r];
      float a = 0.f;
      for (int i=0;i<tot;i++)
        a += ncw[r][i]*af[((size_t)b*NN+ncomp[r][i])*DD + d];
      edgef[(size_t)(e0+r)*DD + d] = a;
    }
  }
}

// =========================================================================
// K3 l2_fused: type MLPs (d/f) + gumbel softmax + ete + U2 = ete@W1+b1
//              + hw2 relu-dot/leaky/full-softmax -> HwT (transposed)
// R=4 edges/block, 256 blocks
// =========================================================================
__global__ void l2_fused_kernel(const float* edgef, const float* etype, const float* g,
                                const float* dW1, const float* db1, const float* dW2, const float* db2,
                                const float* fW1, const float* fb1, const float* fW2, const float* fb2,
                                const float* type_emb,
                                const float* wW1, const float* wb1, const float* wW2, const float* wb2,
                                const float* c0p, const float* Hm, const float* Vm,
                                float* ete_g, float* HwT){
  __shared__ float et4[4][DD+TT+8];   // inputs; later holds ete in [r][0..127]
  __shared__ float part[4*4*HDIM];    // 16KB
  __shared__ float hd4[4][HDIM];      // 4KB; later holds U2
  __shared__ float w2s[HDIM*KK];      // 8KB; [0..255] later holds w_W2
  __shared__ float redsm[256];
  __shared__ float wred[16];
  __shared__ float facs[4];
  __shared__ float zz[4][KK];
  __shared__ float pzs[4][KK];
  __shared__ float fdv[4][KK];
  int e0 = blockIdx.x*4;
  int b  = e0 >> 9;
  int t  = threadIdx.x;               // 256
  const int KW = DD+TT;               // 136

  for (int i=t;i<4*KW;i+=256){
    int r=i/KW, cc=i%KW;
    et4[r][cc] = (cc<DD) ? edgef[(size_t)(e0+r)*DD+cc] : etype[(size_t)(e0+r)*TT + (cc-DD)];
  }
  for (int i=t;i<HDIM*KK;i+=256) w2s[i] = dW2[i];
  __syncthreads();
  int c=(t&63)*4, ks=t>>6;
  // pass d: hd = relu(et@dW1 + db1)
  {
    float4 a[4];
    #pragma unroll
    for (int r=0;r<4;r++) a[r]=make_float4(0.f,0.f,0.f,0.f);
    #pragma unroll 4
    for (int i=ks*34;i<ks*34+34;i++){
      float4 w = *(const float4*)&dW1[(size_t)i*HDIM+c];
      #pragma unroll
      for (int r=0;r<4;r++) f4fma(a[r], et4[r][i], w);
    }
    #pragma unroll
    for (int r=0;r<4;r++) *(float4*)&part[(ks*4+r)*HDIM+c]=a[r];
  }
  __syncthreads();
  {
    float bd = db1[t];
    #pragma unroll
    for (int r=0;r<4;r++){
      float s = (part[(0*4+r)*HDIM+t]+part[(1*4+r)*HDIM+t])
              + (part[(2*4+r)*HDIM+t]+part[(3*4+r)*HDIM+t]);
      hd4[r][t] = fmaxf(s+bd, 0.f);
    }
  }
  __syncthreads();
  // pass f: factor
  {
    float4 a[4];
    #pragma unroll
    for (int r=0;r<4;r++) a[r]=make_float4(0.f,0.f,0.f,0.f);
    #pragma unroll 4
    for (int i=ks*34;i<ks*34+34;i++){
      float4 w = *(const float4*)&fW1[(size_t)i*HDIM+c];
      #pragma unroll
      for (int r=0;r<4;r++) f4fma(a[r], et4[r][i], w);
    }
    #pragma unroll
    for (int r=0;r<4;r++) *(float4*)&part[(ks*4+r)*HDIM+c]=a[r];
  }
  __syncthreads();
  {
    float bf = fb1[t], fw = fW2[t];
    float v4[4];
    #pragma unroll
    for (int r=0;r<4;r++){
      float s = (part[(0*4+r)*HDIM+t]+part[(1*4+r)*HDIM+t])
              + (part[(2*4+r)*HDIM+t]+part[(3*4+r)*HDIM+t]);
      v4[r] = fmaxf(s+bf,0.f)*fw;
    }
    block_reduce4_sum(v4, wred);
    if (t<4) facs[t] = 1.f/(1.f+expf(-(v4[t]+fb2[0])));
  }
  // logits: t -> (r=t>>6, k=(t>>3)&7, j=t&7)
  {
    int rr_ = t>>6, kk_ = (t>>3)&7, jj_ = t&7;
    float lp = 0.f;
    #pragma unroll 4
    for (int h=jj_*32; h<jj_*32+32; h++) lp += hd4[rr_][h]*w2s[h*KK + kk_];
    redsm[t] = lp;
  }
  __syncthreads();
  if (t < 32){
    int r = t>>3, k = t&7;
    float s = db2[k] + g[(size_t)(e0+r)*KK + k];
    #pragma unroll
    for (int j=0;j<8;j++) s += redsm[(r<<6)|(k<<3)|j];
    zz[r][k] = s*2.0f;               // /tau, tau=0.5
  }
  __syncthreads();
  if (t < 32){
    int r = t>>3, k = t&7;
    float m = zz[r][0];
    #pragma unroll
    for (int k2=1;k2<KK;k2++) m = fmaxf(m, zz[r][k2]);
    pzs[r][k] = expf(zz[r][k]-m);
  }
  __syncthreads();
  if (t < 32){
    int r = t>>3, k = t&7;
    float s = 0.f;
    #pragma unroll
    for (int k2=0;k2<KK;k2++) s += pzs[r][k2];
    fdv[r][k] = facs[r]*pzs[r][k]/s;
  }
  __syncthreads();
  // ete -> et4[r][0..127] (+ global for msg)
  {
    int d = t&127;
    #pragma unroll
    for (int rr=0;rr<2;rr++){
      int r = 2*rr + (t>>7);
      float a = 0.f;
      #pragma unroll
      for (int k=0;k<KK;k++) a += fdv[r][k]*type_emb[(size_t)k*DD + d];
      et4[r][d] = a;
      ete_g[(size_t)(e0+r)*DD + d] = a;
    }
    // stage w_W2 for the hw2 phase (w2s[0..255] is dead after logits)
    w2s[t] = wW2[t];
  }
  __syncthreads();
  // U2 = ete@wW1[:D]+wb1 -> hd4
  {
    float4 a[4];
    #pragma unroll
    for (int r=0;r<4;r++) a[r]=make_float4(0.f,0.f,0.f,0.f);
    #pragma unroll 8
    for (int i=ks*32;i<ks*32+32;i++){
      float4 w = *(const float4*)&wW1[(size_t)i*HDIM+c];
      #pragma unroll
      for (int r=0;r<4;r++) f4fma(a[r], et4[r][i], w);
    }
    #pragma unroll
    for (int r=0;r<4;r++) *(float4*)&part[(ks*4+r)*HDIM+c]=a[r];
  }
  __syncthreads();
  {
    float bv = wb1[t];
    #pragma unroll
    for (int r=0;r<4;r++){
      float s = (part[(0*4+r)*HDIM+t]+part[(1*4+r)*HDIM+t])
              + (part[(2*4+r)*HDIM+t]+part[(3*4+r)*HDIM+t]);
      hd4[r][t] = s + bv;            // U2
    }
  }
  __syncthreads();
  // hw2: relu-dot + leaky + full softmax over n, write transposed
  {
    int n = t;
    const float4* Vrow = (const float4*)(Vm + ((size_t)(b*NN)+n)*HDIM);
    float acc[4]={0.f,0.f,0.f,0.f};
    #pragma unroll 4
    for (int ii=0;ii<HDIM/4;ii++){
      float4 v = Vrow[ii];
      float w0=w2s[4*ii+0], w1=w2s[4*ii+1], wc=w2s[4*ii+2], w3=w2s[4*ii+3];
      #pragma unroll
      for (int r=0;r<4;r++){
        acc[r] += fmaxf(hd4[r][4*ii+0]+v.x,0.f)*w0
                + fmaxf(hd4[r][4*ii+1]+v.y,0.f)*w1
                + fmaxf(hd4[r][4*ii+2]+v.z,0.f)*wc
                + fmaxf(hd4[r][4*ii+3]+v.w,0.f)*w3;
      }
    }
    float b2v = wb2[0];
    float c0 = c0p[0];
    float x[4], hv[4];
    #pragma unroll
    for (int r=0;r<4;r++){
      hv[r] = Hm[(size_t)(e0+r)*NN + n];
      float raw = (hv[r]!=0.f) ? (acc[r]+b2v) : c0;
      x[r] = raw>0.f ? raw : 0.01f*raw;
    }
    float m4[4]={x[0],x[1],x[2],x[3]};
    block_reduce4_max(m4, wred);
    float p4[4];
    #pragma unroll
    for (int r=0;r<4;r++) p4[r]=expf(x[r]-m4[r]);
    float s4[4]={p4[0],p4[1],p4[2],p4[3]};
    block_reduce4_sum(s4, wred);
    int eb = e0 & 511;
    float4 o4;
    o4.x = (hv[0]!=0.f)? p4[0]/s4[0] : 0.f;
    o4.y = (hv[1]!=0.f)? p4[1]/s4[1] : 0.f;
    o4.z = (hv[2]!=0.f)? p4[2]/s4[2] : 0.f;
    o4.w = (hv[3]!=0.f)? p4[3]/s4[3] : 0.f;
    *(float4*)(HwT + ((size_t)(b*NN)+n)*EE + eb) = o4;
  }
}

// =========================================================================
// K4 msg: compact Hw2T column then gather [edgef|ete]; agent_feat
// =========================================================================
__global__ void msg_kernel(const float* HwT, const float* edgef, const float* ete,
                           const float* af, float* agf){
  __shared__ int   ecomp[EE];
  __shared__ float wcomp[EE];
  __shared__ int wcnt[4];
  int bn = blockIdx.x; int b = bn>>8; int f = threadIdx.x; // 256 (4 waves)
  int lane = f & 63, wid = f >> 6;
  const float* wrow = HwT + (size_t)bn*EE;
  int total = 0;
  #pragma unroll
  for (int p=0;p<2;p++){
    int e = p*256 + f;
    float w = wrow[e];
    bool pred = (w != 0.f);
    unsigned long long mask = __ballot(pred);
    if (lane==0) wcnt[wid] = __popcll(mask);
    int off = __popcll(mask & ((1ull<<lane)-1ull));
    __syncthreads();
    int wb = total;
    for (int ww=0; ww<wid; ww++) wb += wcnt[ww];
    if (pred){ ecomp[wb+off] = e; wcomp[wb+off] = w; }
    total += wcnt[0]+wcnt[1]+wcnt[2]+wcnt[3];
    __syncthreads();
  }
  float acc = 0.f;
  const float* srcbase = (f < DD) ? (edgef + (size_t)b*EE*DD + f)
                                  : (ete   + (size_t)b*EE*DD + (f-DD));
  for (int i=0;i<total;i++){
    acc += wcomp[i] * srcbase[(size_t)ecomp[i]*DD];
  }
  agf[(size_t)bn*(3*DD)+f] = acc;
  if (f < DD) agf[(size_t)bn*(3*DD) + 2*DD + f] = af[(size_t)bn*DD + f];
}

// ---- shared helper: 4 rows x (128->128) dense layer, float4 + 8-way k-split ----
__device__ __forceinline__ void mlp128_lds(const float (*in)[DD], const float* W, const float* bias,
                                           float (*outl)[DD], float* part, int t){
  int c=(t&31)*4, ks=t>>5;
  float4 a[4];
  #pragma unroll
  for (int r=0;r<4;r++) a[r]=make_float4(0.f,0.f,0.f,0.f);
  #pragma unroll 4
  for (int i=ks*16;i<ks*16+16;i++){
    float4 w = *(const float4*)&W[(size_t)i*DD+c];
    #pragma unroll
    for (int r=0;r<4;r++) f4fma(a[r], in[r][i], w);
  }
  #pragma unroll
  for (int r=0;r<4;r++) *(float4*)&part[(ks*4+r)*DD+c]=a[r];
  __syncthreads();
  int cc=t&127, rh=t>>7;
  for (int rr=rh; rr<4; rr+=2){
    float s=0.f;
    #pragma unroll
    for (int k2=0;k2<8;k2++) s+=part[(k2*4+rr)*DD+cc];
    outl[rr][cc]=s+bias[cc];
  }
  __syncthreads();
}

__device__ __forceinline__ void mlp128_glob(const float (*in)[DD], const float* W, const float* bias,
                                            float* dst, int r0, float* part, int t){
  int c=(t&31)*4, ks=t>>5;
  float4 a[4];
  #pragma unroll
  for (int r=0;r<4;r++) a[r]=make_float4(0.f,0.f,0.f,0.f);
  #pragma unroll 4
  for (int i=ks*16;i<ks*16+16;i++){
    float4 w = *(const float4*)&W[(size_t)i*DD+c];
    #pragma unroll
    for (int r=0;r<4;r++) f4fma(a[r], in[r][i], w);
  }
  #pragma unroll
  for (int r=0;r<4;r++) *(float4*)&part[(ks*4+r)*DD+c]=a[r];
  __syncthreads();
  int cc=t&127, rh=t>>7;
  for (int rr=rh; rr<4; rr+=2){
    float s=0.f;
    #pragma unroll
    for (int k2=0;k2<8;k2++) s+=part[(k2*4+rr)*DD+cc];
    dst[(size_t)(r0+rr)*DD+cc]=s+bias[cc];
  }
  __syncthreads();
}

// K5 q2kv: merged q2 (blocks 0..127) and k2/v2 (blocks 128..255), R=4
__global__ void q2kv_kernel(const float* agf, const float* qW, const float* qb,
                            const float* iqW, const float* iqb,
                            const float* pf,
                            const float* kW, const float* kb, const float* ikW, const float* ikb,
                            const float* vW, const float* vb, const float* ivW, const float* ivb,
                            float* q2, float* k2, float* v2){
  __shared__ float xs[4][3*DD];     // 6KB
  __shared__ float bufA[4][DD];     // 2KB
  __shared__ float bufB[4][DD];     // 2KB
  __shared__ float part[8*4*DD];    // 16KB
  int t = threadIdx.x;              // 256
  if (blockIdx.x < 128){
    int r0 = blockIdx.x*4;
    #pragma unroll
    for (int r=0;r<4;r++)
      for (int cc=t;cc<3*DD;cc+=256) xs[r][cc] = agf[(size_t)(r0+r)*(3*DD)+cc];
    __syncthreads();
    int c=(t&31)*4, ks=t>>5;
    float4 a[4];
    #pragma unroll
    for (int r=0;r<4;r++) a[r]=make_float4(0.f,0.f,0.f,0.f);
    #pragma unroll 4
    for (int i=ks*48;i<ks*48+48;i++){
      float4 w = *(const float4*)&qW[(size_t)i*DD+c];
      #pragma unroll
      for (int r=0;r<4;r++) f4fma(a[r], xs[r][i], w);
    }
    #pragma unroll
    for (int r=0;r<4;r++) *(float4*)&part[(ks*4+r)*DD+c]=a[r];
    __syncthreads();
    int cc=t&127, rh=t>>7;
    for (int rr=rh; rr<4; rr+=2){
      float s=0.f;
      #pragma unroll
      for (int k2_=0;k2_<8;k2_++) s+=part[(k2_*4+rr)*DD+cc];
      bufA[rr][cc]=s+qb[cc];
    }
    __syncthreads();
    mlp128_glob(bufA, iqW, iqb, q2, r0, part, t);
  } else {
    int r0 = (blockIdx.x-128)*4;
    for (int i=t;i<4*DD;i+=256) bufA[i>>7][i&127] = pf[(size_t)(r0+(i>>7))*DD + (i&127)];
    __syncthreads();
    mlp128_lds (bufA, kW, kb, bufB, part, t);
    mlp128_glob(bufB, ikW, ikb, k2, r0, part, t);
    mlp128_lds (bufA, vW, vb, bufB, part, t);
    mlp128_glob(bufB, ivW, ivb, v2, r0, part, t);
  }
}

// K6 attn2: 4-head cross attention + out-proj, R=2 q-rows/block, 256 blocks
__global__ void attn2_kernel(const float* q2, const float* k2, const float* v2,
                             const float* op_W, const float* op_b, float* pnew){
  __shared__ float qr[2][DD];
  __shared__ float att[2][4][PP+1];
  __shared__ float o_l[2][DD];
  __shared__ float part[8*2*DD];
  int r0 = blockIdx.x*2; int b = r0 >> 8; int t = threadIdx.x;
  for (int i=t;i<2*DD;i+=256) qr[i>>7][i&127] = q2[(size_t)(r0+(i>>7))*DD + (i&127)];
  __syncthreads();
  const float scale = 0.17677669529663687f;
  const float* krow = k2 + ((size_t)(b*PP) + t)*DD;
  #pragma unroll
  for (int h=0;h<4;h++){
    const float4* k4 = (const float4*)(krow + h*32);
    float s[2]={0.f,0.f};
    #pragma unroll
    for (int jj=0;jj<8;jj++){
      float4 kk = k4[jj];
      #pragma unroll
      for (int r=0;r<2;r++){
        s[r] += qr[r][h*32+jj*4+0]*kk.x + qr[r][h*32+jj*4+1]*kk.y
              + qr[r][h*32+jj*4+2]*kk.z + qr[r][h*32+jj*4+3]*kk.w;
      }
    }
    #pragma unroll
    for (int r=0;r<2;r++) att[r][h][t] = s[r]*scale;
  }
  __syncthreads();
  {
    int lane = t & 63, wid = t >> 6;
    for (int q = wid; q < 8; q += 4){
      int r = q >> 2, h = q & 3;
      float v0 = att[r][h][lane],     v1 = att[r][h][lane+64],
            ve = att[r][h][lane+128], v3 = att[r][h][lane+192];
      float m = fmaxf(fmaxf(v0,v1), fmaxf(ve,v3));
      #pragma unroll
      for (int s2=32;s2>0;s2>>=1) m = fmaxf(m, __shfl_xor(m, s2, 64));
      float e0 = expf(v0-m), e1 = expf(v1-m), e2 = expf(ve-m), e3 = expf(v3-m);
      float ss = (e0+e1)+(e2+e3);
      #pragma unroll
      for (int s2=32;s2>0;s2>>=1) ss += __shfl_xor(ss, s2, 64);
      float inv = 1.f/ss;
      att[r][h][lane] = e0*inv; att[r][h][lane+64] = e1*inv;
      att[r][h][lane+128] = e2*inv; att[r][h][lane+192] = e3*inv;
    }
  }
  __syncthreads();
  int c=(t&31)*4, ps=t>>5; int h2 = c>>5;
  {
    float4 acc[2];
    #pragma unroll
    for (int r=0;r<2;r++) acc[r]=make_float4(0.f,0.f,0.f,0.f);
    #pragma unroll 4
    for (int i=0;i<32;i++){
      int p = ps*32+i;
      float4 v = *(const float4*)&v2[((size_t)(b*PP)+p)*DD + c];
      #pragma unroll
      for (int r=0;r<2;r++) f4fma(acc[r], att[r][h2][p], v);
    }
    #pragma unroll
    for (int r=0;r<2;r++) *(float4*)&part[(ps*2+r)*DD+c]=acc[r];
  }
  __syncthreads();
  {
    int cc=t&127, r=t>>7;
    float s=0.f;
    #pragma unroll
    for (int k2_=0;k2_<8;k2_++) s+=part[(k2_*2+r)*DD+cc];
    o_l[r][cc]=s;
  }
  __syncthreads();
  {
    float4 a2[2];
    #pragma unroll
    for (int r=0;r<2;r++) a2[r]=make_float4(0.f,0.f,0.f,0.f);
    #pragma unroll 4
    for (int i=ps*16;i<ps*16+16;i++){
      float4 w = *(const float4*)&op_W[(size_t)i*DD + c];
      #pragma unroll
      for (int r=0;r<2;r++) f4fma(a2[r], o_l[r][i], w);
    }
    #pragma unroll
    for (int r=0;r<2;r++) *(float4*)&part[(ps*2+r)*DD+c]=a2[r];
  }
  __syncthreads();
  {
    int cc=t&127, r=t>>7;
    float s=0.f;
    #pragma unroll
    for (int k2_=0;k2_<8;k2_++) s+=part[(k2_*2+r)*DD+cc];
    pnew[(size_t)(r0+r)*DD+cc]=s+op_b[cc];
  }
}

// K7 final2: agent_new = MLP([agf, pnew]), R=2 rows/block, 256 blocks
__global__ void final2_kernel(const float* agf, const float* pnewv,
                              const float* oW1, const float* ob1,
                              const float* oW2, const float* ob2, float* anew){
  __shared__ float xs[2][4*DD];
  __shared__ float hid[2][HDIM];
  __shared__ float part[4*2*HDIM];
  int r0 = blockIdx.x*2; int t = threadIdx.x;
  for (int i=t;i<2*(4*DD);i+=256){
    int r = i>>9, cc = i&511;
    xs[r][cc] = (cc<3*DD) ? agf[(size_t)(r0+r)*(3*DD)+cc]
                          : pnewv[(size_t)(r0+r)*DD + (cc-3*DD)];
  }
  __syncthreads();
  {
    int c=(t&63)*4, ks=t>>6;
    float4 acc[2];
    #pragma unroll
    for (int r=0;r<2;r++) acc[r]=make_float4(0.f,0.f,0.f,0.f);
    #pragma unroll 8
    for (int i=ks*128;i<ks*128+128;i++){
      float4 w = *(const float4*)&oW1[(size_t)i*HDIM+c];
      #pragma unroll
      for (int r=0;r<2;r++) f4fma(acc[r], xs[r][i], w);
    }
    #pragma unroll
    for (int r=0;r<2;r++) *(float4*)&part[(ks*2+r)*HDIM+c]=acc[r];
  }
  __syncthreads();
  {
    float bv = ob1[t];
    #pragma unroll
    for (int r=0;r<2;r++){
      float s = (part[(0*2+r)*HDIM+t]+part[(1*2+r)*HDIM+t])
              + (part[(2*2+r)*HDIM+t]+part[(3*2+r)*HDIM+t]);
      hid[r][t] = fmaxf(s+bv, 0.f);
    }
  }
  __syncthreads();
  {
    int c2=(t&31)*4, ks2=t>>5;
    float4 a2[2];
    #pragma unroll
    for (int r=0;r<2;r++) a2[r]=make_float4(0.f,0.f,0.f,0.f);
    #pragma unroll 8
    for (int h=ks2*32;h<ks2*32+32;h++){
      float4 w = *(const float4*)&oW2[(size_t)h*DD+c2];
      #pragma unroll
      for (int r=0;r<2;r++) f4fma(a2[r], hid[r][h], w);
    }
    #pragma unroll
    for (int r=0;r<2;r++) *(float4*)&part[(ks2*2+r)*DD+c2]=a2[r];
  }
  __syncthreads();
  {
    int cc=t&127, r=t>>7;
    float s=0.f;
    #pragma unroll
    for (int k2_=0;k2_<8;k2_++) s+=part[(k2_*2+r)*DD+cc];
    anew[(size_t)(r0+r)*DD+cc]=s+ob2[cc];
  }
}

extern "C" void kernel_launch(void* const* d_in, const int* in_sizes, int n_in,
                              void* d_out, int out_size, void* d_ws, size_t ws_size,
                              hipStream_t stream) {
  const float* af       = (const float*)d_in[0];
  const float* at       = (const float*)d_in[1];
  const float* pf       = (const float*)d_in[2];
  const float* Hm       = (const float*)d_in[3];
  const float* type_emb = (const float*)d_in[4];
  const float* w_W1 = (const float*)d_in[5];
  const float* w_b1 = (const float*)d_in[6];
  const float* w_W2 = (const float*)d_in[7];
  const float* w_b2 = (const float*)d_in[8];
  const float* d_W1 = (const float*)d_in[9];
  const float* d_b1 = (const float*)d_in[10];
  const float* d_W2 = (const float*)d_in[11];
  const float* d_b2 = (const float*)d_in[12];
  const float* f_W1 = (const float*)d_in[13];
  const float* f_b1 = (const float*)d_in[14];
  const float* f_W2 = (const float*)d_in[15];
  const float* f_b2 = (const float*)d_in[16];
  const float* o_W1 = (const float*)d_in[17];
  const float* o_b1 = (const float*)d_in[18];
  const float* o_W2 = (const float*)d_in[19];
  const float* o_b2 = (const float*)d_in[20];
  const float* q_W  = (const float*)d_in[21];
  const float* q_b  = (const float*)d_in[22];
  const float* k_W  = (const float*)d_in[23];
  const float* k_b  = (const float*)d_in[24];
  const float* v_W  = (const float*)d_in[25];
  const float* v_b  = (const float*)d_in[26];
  const float* iq_W = (const float*)d_in[27];
  const float* iq_b = (const float*)d_in[28];
  const float* ik_W = (const float*)d_in[29];
  const float* ik_b = (const float*)d_in[30];
  const float* iv_W = (const float*)d_in[31];
  const float* iv_b = (const float*)d_in[32];
  const float* op_W = (const float*)d_in[33];
  const float* op_b = (const float*)d_in[34];

  float* ws   = (float*)d_ws;
  float* out  = (float*)d_out;
  float* anew = out;                 // (B,N,D)
  float* pnew = out + BB*NN*DD;      // (B,N,D)

  prep_kernel<<<16+BB*EE+128, 256, 0, stream>>>(
      ws+WS_G, ws+WS_C0, w_b1, w_W2, w_b2,
      Hm, af, at, ws+WS_EF0, ws+WS_ETYPE, w_W1, ws+WS_V);
  l1_fused_kernel<<<256,256,0,stream>>>(
      ws+WS_EF0, ws+WS_V, Hm, af, w_W1, w_b1, w_W2, w_b2, ws+WS_EDGEF);
  l2_fused_kernel<<<256,256,0,stream>>>(
      ws+WS_EDGEF, ws+WS_ETYPE, ws+WS_G,
      d_W1,d_b1,d_W2,d_b2, f_W1,f_b1,f_W2,f_b2, type_emb,
      w_W1, w_b1, w_W2, w_b2, ws+WS_C0, Hm, ws+WS_V,
      ws+WS_ETE, ws+WS_HWT);
  msg_kernel<<<BB*NN,256,0,stream>>>(ws+WS_HWT, ws+WS_EDGEF, ws+WS_ETE, af, ws+WS_AGF);
  q2kv_kernel<<<256,256,0,stream>>>(ws+WS_AGF, q_W,q_b,iq_W,iq_b, pf,
                                    k_W,k_b,ik_W,ik_b, v_W,v_b,iv_W,iv_b,
                                    ws+WS_Q2, ws+WS_K2, ws+WS_V2);
  attn2_kernel<<<256,256,0,stream>>>(ws+WS_Q2, ws+WS_K2, ws+WS_V2, op_W, op_b, pnew);
  final2_kernel<<<256,256,0,stream>>>(ws+WS_AGF, pnew, o_W1,o_b1,o_W2,o_b2, anew);
}

// Round 6
// 91.776 us; speedup vs baseline: 2.3142x; 1.1374x over previous
//
#include <hip/hip_runtime.h>
#include <math.h>

#define BB 2
#define NN 256
#define EE 512
#define PP 256
#define DD 128
#define TT 8
#define KK 8
#define HDIM 256

// workspace offsets (floats)
#define WS_G      0          // B*E*K = 8192
#define WS_C0     8192       // 64
#define WS_EF0    8256       // B*E*D = 131072
#define WS_ETYPE  139328     // B*E*T = 8192
#define WS_V      147520     // B*N*HD = 131072
#define WS_EDGEF  278592     // B*E*D = 131072
#define WS_ETE    409664     // B*E*D = 131072
#define WS_HWT    540736     // B*N*E = 262144 (transposed Hw2)
#define WS_AGF    802880     // B*N*3D = 196608
#define WS_Q2     999488     // 65536
#define WS_K2     1065024    // 65536
#define WS_V2     1130560    // 65536
// total 1196096 floats = 4.78 MB

// prep grid roles
#define GB_INC  16
#define GB_V    1040
#define GB_KV   1168
#define GB_END  1296

__device__ inline unsigned rotl32(unsigned x, int d){ return (x<<d)|(x>>(32-d)); }

__device__ inline float bits_to_gumbel(unsigned bits){
  float f = __uint_as_float((bits>>9)|0x3f800000u) - 1.0f;
  const float minv = 1e-6f;
  const float maxv = 1.0f - 1e-6f;
  float u = f*(maxv-minv) + minv;
  u = fmaxf(minv, u);
  return -logf(-logf(u));
}

__device__ __forceinline__ void f4fma(float4& a, float x, const float4& w){
  a.x += x*w.x; a.y += x*w.y; a.z += x*w.z; a.w += x*w.w;
}

// ---- block-wide reduction of 4 values over 256 threads (4 waves) ----
__device__ __forceinline__ void block_reduce4_max(float v[4], float* wred){
  int lane = threadIdx.x & 63, wid = threadIdx.x >> 6;
  #pragma unroll
  for (int s=32;s>0;s>>=1){
    #pragma unroll
    for (int r=0;r<4;r++){ float o = __shfl_xor(v[r], s, 64); v[r] = fmaxf(v[r],o); }
  }
  if (lane==0){
    #pragma unroll
    for (int r=0;r<4;r++) wred[wid*4+r]=v[r];
  }
  __syncthreads();
  #pragma unroll
  for (int r=0;r<4;r++)
    v[r] = fmaxf(fmaxf(wred[0*4+r],wred[1*4+r]), fmaxf(wred[2*4+r],wred[3*4+r]));
  __syncthreads();
}

__device__ __forceinline__ void block_reduce4_sum(float v[4], float* wred){
  int lane = threadIdx.x & 63, wid = threadIdx.x >> 6;
  #pragma unroll
  for (int s=32;s>0;s>>=1){
    #pragma unroll
    for (int r=0;r<4;r++){ v[r] += __shfl_xor(v[r], s, 64); }
  }
  if (lane==0){
    #pragma unroll
    for (int r=0;r<4;r++) wred[wid*4+r]=v[r];
  }
  __syncthreads();
  #pragma unroll
  for (int r=0;r<4;r++)
    v[r] = (wred[0*4+r]+wred[1*4+r]) + (wred[2*4+r]+wred[3*4+r]);
  __syncthreads();
}

// ---- shared helper: 4 rows x (128->128) dense layer, float4 + 8-way k-split ----
__device__ __forceinline__ void mlp128_lds(const float (*in)[DD], const float* W, const float* bias,
                                           float (*outl)[DD], float* part, int t){
  int c=(t&31)*4, ks=t>>5;
  float4 a[4];
  #pragma unroll
  for (int r=0;r<4;r++) a[r]=make_float4(0.f,0.f,0.f,0.f);
  #pragma unroll 4
  for (int i=ks*16;i<ks*16+16;i++){
    float4 w = *(const float4*)&W[(size_t)i*DD+c];
    #pragma unroll
    for (int r=0;r<4;r++) f4fma(a[r], in[r][i], w);
  }
  #pragma unroll
  for (int r=0;r<4;r++) *(float4*)&part[(ks*4+r)*DD+c]=a[r];
  __syncthreads();
  int cc=t&127, rh=t>>7;
  for (int rr=rh; rr<4; rr+=2){
    float s=0.f;
    #pragma unroll
    for (int k2=0;k2<8;k2++) s+=part[(k2*4+rr)*DD+cc];
    outl[rr][cc]=s+bias[cc];
  }
  __syncthreads();
}

__device__ __forceinline__ void mlp128_glob(const float (*in)[DD], const float* W, const float* bias,
                                            float* dst, int r0, float* part, int t){
  int c=(t&31)*4, ks=t>>5;
  float4 a[4];
  #pragma unroll
  for (int r=0;r<4;r++) a[r]=make_float4(0.f,0.f,0.f,0.f);
  #pragma unroll 4
  for (int i=ks*16;i<ks*16+16;i++){
    float4 w = *(const float4*)&W[(size_t)i*DD+c];
    #pragma unroll
    for (int r=0;r<4;r++) f4fma(a[r], in[r][i], w);
  }
  #pragma unroll
  for (int r=0;r<4;r++) *(float4*)&part[(ks*4+r)*DD+c]=a[r];
  __syncthreads();
  int cc=t&127, rh=t>>7;
  for (int rr=rh; rr<4; rr+=2){
    float s=0.f;
    #pragma unroll
    for (int k2=0;k2<8;k2++) s+=part[(k2*4+rr)*DD+cc];
    dst[(size_t)(r0+rr)*DD+cc]=s+bias[cc];
  }
  __syncthreads();
}

// =========================================================================
// K1 prep: gumbel+c0 (0..15) | incidence (16..1039) | V-MLP (1040..1167)
//          | k2/v2 chains from pf (1168..1295)
// =========================================================================
__global__ void prep_kernel(float* g, float* c0, const float* w_b1,
                            const float* w_W2, const float* w_b2,
                            const float* Hm, const float* af, const float* at,
                            float* ef0, float* etype,
                            const float* wW1, float* Vout,
                            const float* pf,
                            const float* kW, const float* kb, const float* ikW, const float* ikb,
                            const float* vW, const float* vb, const float* ivW, const float* ivb,
                            float* k2, float* v2){
  __shared__ int   ecomp[NN];
  __shared__ int   wcnt[4];
  __shared__ float accl[2][DD];
  __shared__ float acctl[2][TT];
  __shared__ float xs[4][DD];
  __shared__ float part[4*4*HDIM];   // 16KB (also used as 8*4*DD by kv helpers)
  __shared__ float wred[16];
  __shared__ float bufB[4][DD];
  int blk = blockIdx.x;
  int t = threadIdx.x;               // 256
  int lane = t & 63, wid = t >> 6;

  if (blk < GB_INC){
    // ---- gumbel: j = blk*256 + t ----
    int j = blk*256 + t;
    {
      const unsigned k0=0u, k1=42u;
      const unsigned ks2 = k0^k1^0x1BD11BDAu;
      unsigned x0 = (unsigned)j, x1 = (unsigned)j + 4096u;
      const int r0[4]={13,15,26,6}, r1[4]={17,29,16,24};
      x0 += k0; x1 += k1;
      #pragma unroll
      for(int i=0;i<4;i++){ x0+=x1; x1=rotl32(x1,r0[i]); x1^=x0; }
      x0+=k1; x1+=ks2+1u;
      #pragma unroll
      for(int i=0;i<4;i++){ x0+=x1; x1=rotl32(x1,r1[i]); x1^=x0; }
      x0+=ks2; x1+=k0+2u;
      #pragma unroll
      for(int i=0;i<4;i++){ x0+=x1; x1=rotl32(x1,r0[i]); x1^=x0; }
      x0+=k0; x1+=k1+3u;
      #pragma unroll
      for(int i=0;i<4;i++){ x0+=x1; x1=rotl32(x1,r1[i]); x1^=x0; }
      x0+=k1; x1+=ks2+4u;
      #pragma unroll
      for(int i=0;i<4;i++){ x0+=x1; x1=rotl32(x1,r0[i]); x1^=x0; }
      x0+=ks2; x1+=k0+5u;
      g[j]      = bits_to_gumbel(x0);
      g[j+4096] = bits_to_gumbel(x1);
    }
    if (blk == 0){
      float v4[4];
      v4[0] = fmaxf(w_b1[t],0.f)*w_W2[t]; v4[1]=0.f; v4[2]=0.f; v4[3]=0.f;
      block_reduce4_sum(v4, wred);
      if (t==0) c0[0] = v4[0] + w_b2[0];
    }
  } else if (blk < GB_V){
    // ---- incidence: compact H row then stream ----
    int be = blk - GB_INC;
    int b  = be >> 9;
    const float* Hrow = Hm + (size_t)be*NN;
    int n = t;
    bool pred = (Hrow[n] != 0.f);
    unsigned long long mask = __ballot(pred);
    if (lane==0) wcnt[wid] = __popcll(mask);
    int off = __popcll(mask & ((1ull<<lane)-1ull));
    __syncthreads();
    int wb = 0;
    for (int ww=0; ww<wid; ww++) wb += wcnt[ww];
    if (pred) ecomp[wb+off] = n;
    int total = wcnt[0]+wcnt[1]+wcnt[2]+wcnt[3];
    __syncthreads();
    int d = t & 127, h2 = t >> 7;
    float acc = 0.f, acct = 0.f;
    for (int i=h2; i<total; i+=2){
      int n2 = ecomp[i];
      acc += af[((size_t)b*NN+n2)*DD + d];
      if (d < TT) acct += at[((size_t)b*NN+n2)*TT + d];
    }
    accl[h2][d] = acc;
    if (d < TT) acctl[h2][d] = acct;
    __syncthreads();
    if (t < DD) ef0[(size_t)be*DD + t] = accl[0][t] + accl[1][t];
    if (t < TT) etype[(size_t)be*TT + t] = acctl[0][t] + acctl[1][t];
  } else if (blk < GB_KV){
    // ---- V = af @ wW1[D:] (no bias), R=4 rows ----
    int r0 = (blk - GB_V)*4;
    const float* W = wW1 + (size_t)DD*HDIM;
    for (int i=t;i<4*DD;i+=256) xs[i>>7][i&127] = af[(size_t)(r0+(i>>7))*DD + (i&127)];
    __syncthreads();
    int c = (t&63)*4, ks = t>>6;
    float4 acc[4];
    #pragma unroll
    for (int r=0;r<4;r++) acc[r]=make_float4(0.f,0.f,0.f,0.f);
    #pragma unroll 8
    for (int i=ks*32; i<ks*32+32; i++){
      float4 w = *(const float4*)&W[(size_t)i*HDIM + c];
      #pragma unroll
      for (int r=0;r<4;r++) f4fma(acc[r], xs[r][i], w);
    }
    #pragma unroll
    for (int r=0;r<4;r++) *(float4*)&part[(ks*4+r)*HDIM + c] = acc[r];
    __syncthreads();
    #pragma unroll
    for (int r=0;r<4;r++){
      float s = (part[(0*4+r)*HDIM+t] + part[(1*4+r)*HDIM+t])
              + (part[(2*4+r)*HDIM+t] + part[(3*4+r)*HDIM+t]);
      Vout[(size_t)(r0+r)*HDIM + t] = s;
    }
  } else {
    // ---- k2/v2 chains from pf, R=4 rows ----
    int r0 = (blk - GB_KV)*4;
    for (int i=t;i<4*DD;i+=256) xs[i>>7][i&127] = pf[(size_t)(r0+(i>>7))*DD + (i&127)];
    __syncthreads();
    mlp128_lds (xs, kW, kb, bufB, part, t);
    mlp128_glob(bufB, ikW, ikb, k2, r0, part, t);
    mlp128_lds (xs, vW, vb, bufB, part, t);
    mlp128_glob(bufB, ivW, ivb, v2, r0, part, t);
  }
}

// =========================================================================
// K2 l1_fused: U1 MLP + relu-dot + masked softmax + aggregate (Hw in LDS)
// R=4 edges/block, 256 blocks
// =========================================================================
__global__ void l1_fused_kernel(const float* ef0, const float* Vm, const float* Hm,
                                const float* af, const float* wW1, const float* wb1,
                                const float* wW2, const float* wb2, float* edgef){
  __shared__ float xs[4][DD];         // 2KB
  __shared__ float part[4*4*HDIM];    // 16KB
  __shared__ float u[4][HDIM];        // 4KB
  __shared__ float w2l[HDIM];         // 1KB
  __shared__ float hwls[4][NN];       // 4KB
  __shared__ float wred[16];
  __shared__ int   ncomp[4][NN];      // 4KB
  __shared__ float ncw[4][NN];        // 4KB
  __shared__ int   ncnt[4];
  int e0 = blockIdx.x*4;
  int b  = e0 >> 9;
  int t  = threadIdx.x;               // 256
  int lane = t & 63, wid = t >> 6;

  for (int i=t;i<4*DD;i+=256) xs[i>>7][i&127] = ef0[(size_t)(e0+(i>>7))*DD + (i&127)];
  w2l[t] = wW2[t];
  __syncthreads();
  // U1 (float4 + 4-way k-split)
  {
    int c = (t&63)*4, ks = t>>6;
    float4 acc[4];
    #pragma unroll
    for (int r=0;r<4;r++) acc[r]=make_float4(0.f,0.f,0.f,0.f);
    #pragma unroll 8
    for (int i=ks*32; i<ks*32+32; i++){
      float4 w = *(const float4*)&wW1[(size_t)i*HDIM + c];
      #pragma unroll
      for (int r=0;r<4;r++) f4fma(acc[r], xs[r][i], w);
    }
    #pragma unroll
    for (int r=0;r<4;r++) *(float4*)&part[(ks*4+r)*HDIM + c] = acc[r];
  }
  __syncthreads();
  {
    float bv = wb1[t];
    #pragma unroll
    for (int r=0;r<4;r++){
      float s = (part[(0*4+r)*HDIM+t] + part[(1*4+r)*HDIM+t])
              + (part[(2*4+r)*HDIM+t] + part[(3*4+r)*HDIM+t]);
      u[r][t] = s + bv;
    }
  }
  __syncthreads();
  // relu-dot over n = t
  int n = t;
  const float4* Vrow = (const float4*)(Vm + ((size_t)(b*NN)+n)*HDIM);
  float acc[4]={0.f,0.f,0.f,0.f};
  #pragma unroll 4
  for (int ii=0;ii<HDIM/4;ii++){
    float4 v = Vrow[ii];
    float w0=w2l[4*ii+0], w1=w2l[4*ii+1], wc=w2l[4*ii+2], w3=w2l[4*ii+3];
    #pragma unroll
    for (int r=0;r<4;r++){
      acc[r] += fmaxf(u[r][4*ii+0]+v.x,0.f)*w0
              + fmaxf(u[r][4*ii+1]+v.y,0.f)*w1
              + fmaxf(u[r][4*ii+2]+v.z,0.f)*wc
              + fmaxf(u[r][4*ii+3]+v.w,0.f)*w3;
    }
  }
  float b2v = wb2[0];
  float x[4], hv[4];
  #pragma unroll
  for (int r=0;r<4;r++){
    hv[r] = Hm[(size_t)(e0+r)*NN + n];
    x[r] = (hv[r]!=0.f) ? (acc[r]+b2v) : 0.f;
  }
  float m4[4]={x[0],x[1],x[2],x[3]};
  block_reduce4_max(m4, wred);
  float p4[4];
  #pragma unroll
  for (int r=0;r<4;r++) p4[r]=expf(x[r]-m4[r]);
  float s4[4]={p4[0],p4[1],p4[2],p4[3]};
  block_reduce4_sum(s4, wred);
  #pragma unroll
  for (int r=0;r<4;r++)
    hwls[r][n] = (hv[r]!=0.f) ? p4[r]/s4[r] : 0.f;
  __syncthreads();
  // per-wave compaction: wave wid owns edge r=wid
  {
    int r = wid;
    int base = 0;
    #pragma unroll
    for (int c4=0;c4<4;c4++){
      int n2 = c4*64 + lane;
      float w = hwls[r][n2];
      bool pred = (w != 0.f);
      unsigned long long mask = __ballot(pred);
      int off = __popcll(mask & ((1ull<<lane)-1ull));
      if (pred){ ncomp[r][base+off] = n2; ncw[r][base+off] = w; }
      base += __popcll(mask);
    }
    if (lane==0) ncnt[r] = base;
  }
  __syncthreads();
  {
    int d = t & 127, eh = t >> 7;
    #pragma unroll
    for (int rr=0;rr<2;rr++){
      int r = eh*2 + rr;
      int tot = ncnt[r];
      float a = 0.f;
      for (int i=0;i<tot;i++)
        a += ncw[r][i]*af[((size_t)b*NN+ncomp[r][i])*DD + d];
      edgef[(size_t)(e0+r)*DD + d] = a;
    }
  }
}

// =========================================================================
// K3 l2_fused: merged d/f MLPs + gumbel softmax + ete + U2 + hw2 -> HwT
// R=4 edges/block, 256 blocks
// =========================================================================
__global__ void l2_fused_kernel(const float* edgef, const float* etype, const float* g,
                                const float* dW1, const float* db1, const float* dW2, const float* db2,
                                const float* fW1, const float* fb1, const float* fW2, const float* fb2,
                                const float* type_emb,
                                const float* wW1, const float* wb1, const float* wW2, const float* wb2,
                                const float* c0p, const float* Hm, const float* Vm,
                                float* ete_g, float* HwT){
  __shared__ float et4[4][DD+TT+8];   // inputs; later holds ete in [r][0..127]
  __shared__ float partD[4*4*HDIM];   // 16KB
  __shared__ float partF[4*4*HDIM];   // 16KB
  __shared__ float hd4[4][HDIM];      // 4KB; later holds U2
  __shared__ float w2s[HDIM*KK];      // 8KB; [0..255] later holds w_W2
  __shared__ float redsm[256];
  __shared__ float wred[16];
  __shared__ float facs[4];
  __shared__ float zz[4][KK];
  __shared__ float pzs[4][KK];
  __shared__ float fdv[4][KK];
  int e0 = blockIdx.x*4;
  int b  = e0 >> 9;
  int t  = threadIdx.x;               // 256
  const int KW = DD+TT;               // 136

  for (int i=t;i<4*KW;i+=256){
    int r=i/KW, cc=i%KW;
    et4[r][cc] = (cc<DD) ? edgef[(size_t)(e0+r)*DD+cc] : etype[(size_t)(e0+r)*TT + (cc-DD)];
  }
  for (int i=t;i<HDIM*KK;i+=256) w2s[i] = dW2[i];
  __syncthreads();
  int c=(t&63)*4, ks=t>>6;
  // merged d+f pass: two weight streams in flight
  {
    float4 ad4[4], af4[4];
    #pragma unroll
    for (int r=0;r<4;r++){ ad4[r]=make_float4(0.f,0.f,0.f,0.f); af4[r]=make_float4(0.f,0.f,0.f,0.f); }
    #pragma unroll 4
    for (int i=ks*34;i<ks*34+34;i++){
      float4 wd = *(const float4*)&dW1[(size_t)i*HDIM+c];
      float4 wf = *(const float4*)&fW1[(size_t)i*HDIM+c];
      #pragma unroll
      for (int r=0;r<4;r++){ float x=et4[r][i]; f4fma(ad4[r],x,wd); f4fma(af4[r],x,wf); }
    }
    #pragma unroll
    for (int r=0;r<4;r++){
      *(float4*)&partD[(ks*4+r)*HDIM+c]=ad4[r];
      *(float4*)&partF[(ks*4+r)*HDIM+c]=af4[r];
    }
  }
  __syncthreads();
  {
    float bd = db1[t];
    float bf = fb1[t], fw = fW2[t];
    float v4[4];
    #pragma unroll
    for (int r=0;r<4;r++){
      float sd = (partD[(0*4+r)*HDIM+t]+partD[(1*4+r)*HDIM+t])
               + (partD[(2*4+r)*HDIM+t]+partD[(3*4+r)*HDIM+t]);
      hd4[r][t] = fmaxf(sd+bd, 0.f);
      float sf = (partF[(0*4+r)*HDIM+t]+partF[(1*4+r)*HDIM+t])
               + (partF[(2*4+r)*HDIM+t]+partF[(3*4+r)*HDIM+t]);
      v4[r] = fmaxf(sf+bf,0.f)*fw;
    }
    block_reduce4_sum(v4, wred);
    if (t<4) facs[t] = 1.f/(1.f+expf(-(v4[t]+fb2[0])));
  }
  // logits: t -> (r=t>>6, k=(t>>3)&7, j=t&7); interleaved h = j + 8*i
  // (bank = (j*8+k)&31 -> 2-way, vs 8-way for the blocked h-partition)
  {
    int rr_ = t>>6, kk_ = (t>>3)&7, jj_ = t&7;
    float lp = 0.f;
    #pragma unroll 4
    for (int i=0;i<32;i++){
      int h = jj_ + 8*i;
      lp += hd4[rr_][h]*w2s[h*KK + kk_];
    }
    redsm[t] = lp;
  }
  __syncthreads();
  if (t < 32){
    int r = t>>3, k = t&7;
    float s = db2[k] + g[(size_t)(e0+r)*KK + k];
    #pragma unroll
    for (int j=0;j<8;j++) s += redsm[(r<<6)|(k<<3)|j];
    zz[r][k] = s*2.0f;               // /tau, tau=0.5
  }
  __syncthreads();
  if (t < 32){
    int r = t>>3, k = t&7;
    float m = zz[r][0];
    #pragma unroll
    for (int k2=1;k2<KK;k2++) m = fmaxf(m, zz[r][k2]);
    pzs[r][k] = expf(zz[r][k]-m);
  }
  __syncthreads();
  if (t < 32){
    int r = t>>3, k = t&7;
    float s = 0.f;
    #pragma unroll
    for (int k2=0;k2<KK;k2++) s += pzs[r][k2];
    fdv[r][k] = facs[r]*pzs[r][k]/s;
  }
  __syncthreads();
  // ete -> et4[r][0..127] (+ global for msg)
  {
    int d = t&127;
    #pragma unroll
    for (int rr=0;rr<2;rr++){
      int r = 2*rr + (t>>7);
      float a = 0.f;
      #pragma unroll
      for (int k=0;k<KK;k++) a += fdv[r][k]*type_emb[(size_t)k*DD + d];
      et4[r][d] = a;
      ete_g[(size_t)(e0+r)*DD + d] = a;
    }
    w2s[t] = wW2[t];   // stage w_W2 for the hw2 phase
  }
  __syncthreads();
  // U2 = ete@wW1[:D]+wb1 -> hd4
  {
    float4 a[4];
    #pragma unroll
    for (int r=0;r<4;r++) a[r]=make_float4(0.f,0.f,0.f,0.f);
    #pragma unroll 8
    for (int i=ks*32;i<ks*32+32;i++){
      float4 w = *(const float4*)&wW1[(size_t)i*HDIM+c];
      #pragma unroll
      for (int r=0;r<4;r++) f4fma(a[r], et4[r][i], w);
    }
    #pragma unroll
    for (int r=0;r<4;r++) *(float4*)&partD[(ks*4+r)*HDIM+c]=a[r];
  }
  __syncthreads();
  {
    float bv = wb1[t];
    #pragma unroll
    for (int r=0;r<4;r++){
      float s = (partD[(0*4+r)*HDIM+t]+partD[(1*4+r)*HDIM+t])
              + (partD[(2*4+r)*HDIM+t]+partD[(3*4+r)*HDIM+t]);
      hd4[r][t] = s + bv;            // U2
    }
  }
  __syncthreads();
  // hw2: relu-dot + leaky + full softmax over n, write transposed
  {
    int n = t;
    const float4* Vrow = (const float4*)(Vm + ((size_t)(b*NN)+n)*HDIM);
    float acc[4]={0.f,0.f,0.f,0.f};
    #pragma unroll 4
    for (int ii=0;ii<HDIM/4;ii++){
      float4 v = Vrow[ii];
      float w0=w2s[4*ii+0], w1=w2s[4*ii+1], wc=w2s[4*ii+2], w3=w2s[4*ii+3];
      #pragma unroll
      for (int r=0;r<4;r++){
        acc[r] += fmaxf(hd4[r][4*ii+0]+v.x,0.f)*w0
                + fmaxf(hd4[r][4*ii+1]+v.y,0.f)*w1
                + fmaxf(hd4[r][4*ii+2]+v.z,0.f)*wc
                + fmaxf(hd4[r][4*ii+3]+v.w,0.f)*w3;
      }
    }
    float b2v = wb2[0];
    float c0 = c0p[0];
    float x[4], hv[4];
    #pragma unroll
    for (int r=0;r<4;r++){
      hv[r] = Hm[(size_t)(e0+r)*NN + n];
      float raw = (hv[r]!=0.f) ? (acc[r]+b2v) : c0;
      x[r] = raw>0.f ? raw : 0.01f*raw;
    }
    float m4[4]={x[0],x[1],x[2],x[3]};
    block_reduce4_max(m4, wred);
    float p4[4];
    #pragma unroll
    for (int r=0;r<4;r++) p4[r]=expf(x[r]-m4[r]);
    float s4[4]={p4[0],p4[1],p4[2],p4[3]};
    block_reduce4_sum(s4, wred);
    int eb = e0 & 511;
    float4 o4;
    o4.x = (hv[0]!=0.f)? p4[0]/s4[0] : 0.f;
    o4.y = (hv[1]!=0.f)? p4[1]/s4[1] : 0.f;
    o4.z = (hv[2]!=0.f)? p4[2]/s4[2] : 0.f;
    o4.w = (hv[3]!=0.f)? p4[3]/s4[3] : 0.f;
    *(float4*)(HwT + ((size_t)(b*NN)+n)*EE + eb) = o4;
  }
}

// =========================================================================
// K4 msgq2: msg (compact Hw2T column + gather) -> agf, then q2 for same row
// 512 blocks (2/CU: q-weight streams overlap across co-resident blocks)
// =========================================================================
__global__ void msgq2_kernel(const float* HwT, const float* edgef, const float* ete,
                             const float* af, const float* qW, const float* qb,
                             const float* iqW, const float* iqb,
                             float* agf, float* q2){
  __shared__ int   ecomp[EE];
  __shared__ float wcomp[EE];
  __shared__ int   wcnt[4];
  __shared__ float agfl[3*DD];
  __shared__ float part[8*DD];
  __shared__ float Qs[DD];
  int bn = blockIdx.x; int b = bn>>8; int f = threadIdx.x; // 256 (4 waves)
  int lane = f & 63, wid = f >> 6;
  const float* wrow = HwT + (size_t)bn*EE;
  int total = 0;
  #pragma unroll
  for (int p=0;p<2;p++){
    int e = p*256 + f;
    float w = wrow[e];
    bool pred = (w != 0.f);
    unsigned long long mask = __ballot(pred);
    if (lane==0) wcnt[wid] = __popcll(mask);
    int off = __popcll(mask & ((1ull<<lane)-1ull));
    __syncthreads();
    int wb = total;
    for (int ww=0; ww<wid; ww++) wb += wcnt[ww];
    if (pred){ ecomp[wb+off] = e; wcomp[wb+off] = w; }
    total += wcnt[0]+wcnt[1]+wcnt[2]+wcnt[3];
    __syncthreads();
  }
  float acc = 0.f;
  const float* srcbase = (f < DD) ? (edgef + (size_t)b*EE*DD + f)
                                  : (ete   + (size_t)b*EE*DD + (f-DD));
  for (int i=0;i<total;i++){
    acc += wcomp[i] * srcbase[(size_t)ecomp[i]*DD];
  }
  agfl[f] = acc;
  agf[(size_t)bn*(3*DD)+f] = acc;
  if (f < DD){
    float av = af[(size_t)bn*DD + f];
    agfl[2*DD+f] = av;
    agf[(size_t)bn*(3*DD) + 2*DD + f] = av;
  }
  __syncthreads();
  // q2 stage1: (1 x 384) @ (384 x 128), 8-way k-split
  int c=(f&31)*4, ks=f>>5;
  {
    float4 a = make_float4(0.f,0.f,0.f,0.f);
    #pragma unroll 4
    for (int i=ks*48;i<ks*48+48;i++){
      float4 w = *(const float4*)&qW[(size_t)i*DD+c];
      f4fma(a, agfl[i], w);
    }
    *(float4*)&part[ks*DD+c]=a;
  }
  __syncthreads();
  if (f<DD){
    float s=0.f;
    #pragma unroll
    for (int k=0;k<8;k++) s+=part[k*DD+f];
    Qs[f]=s+qb[f];
  }
  __syncthreads();
  // q2 stage2: (1 x 128) @ (128 x 128)
  {
    float4 a = make_float4(0.f,0.f,0.f,0.f);
    #pragma unroll 4
    for (int i=ks*16;i<ks*16+16;i++){
      float4 w = *(const float4*)&iqW[(size_t)i*DD+c];
      f4fma(a, Qs[i], w);
    }
    *(float4*)&part[ks*DD+c]=a;
  }
  __syncthreads();
  if (f<DD){
    float s=0.f;
    #pragma unroll
    for (int k=0;k<8;k++) s+=part[k*DD+f];
    q2[(size_t)bn*DD+f]=s+iqb[f];
  }
}

// =========================================================================
// K5 attnfinal: 4-head cross attn + out-proj -> pnew, then final MLP -> anew
// R=2 q-rows/block, 256 blocks
// =========================================================================
__global__ void attnfinal_kernel(const float* q2, const float* k2, const float* v2,
                                 const float* op_W, const float* op_b,
                                 const float* agf,
                                 const float* oW1, const float* ob1,
                                 const float* oW2, const float* ob2,
                                 float* pnew, float* anew){
  __shared__ float qr[2][DD];
  __shared__ float att[2][4][PP+1];
  __shared__ float o_l[2][DD];
  __shared__ float part[8*2*DD];      // 8KB (reused by final stages)
  __shared__ float pnl[2][DD];
  __shared__ float xs[2][4*DD];
  __shared__ float hid[2][HDIM];
  int r0 = blockIdx.x*2; int b = r0 >> 8; int t = threadIdx.x;
  for (int i=t;i<2*DD;i+=256) qr[i>>7][i&127] = q2[(size_t)(r0+(i>>7))*DD + (i&127)];
  __syncthreads();
  const float scale = 0.17677669529663687f;  // 1/sqrt(32)
  const float* krow = k2 + ((size_t)(b*PP) + t)*DD;
  #pragma unroll
  for (int h=0;h<4;h++){
    const float4* k4 = (const float4*)(krow + h*32);
    float s[2]={0.f,0.f};
    #pragma unroll
    for (int jj=0;jj<8;jj++){
      float4 kk = k4[jj];
      #pragma unroll
      for (int r=0;r<2;r++){
        s[r] += qr[r][h*32+jj*4+0]*kk.x + qr[r][h*32+jj*4+1]*kk.y
              + qr[r][h*32+jj*4+2]*kk.z + qr[r][h*32+jj*4+3]*kk.w;
      }
    }
    #pragma unroll
    for (int r=0;r<2;r++) att[r][h][t] = s[r]*scale;
  }
  __syncthreads();
  {
    int lane = t & 63, wid = t >> 6;
    for (int q = wid; q < 8; q += 4){
      int r = q >> 2, h = q & 3;
      float v0 = att[r][h][lane],     v1 = att[r][h][lane+64],
            ve = att[r][h][lane+128], v3 = att[r][h][lane+192];
      float m = fmaxf(fmaxf(v0,v1), fmaxf(ve,v3));
      #pragma unroll
      for (int s2=32;s2>0;s2>>=1) m = fmaxf(m, __shfl_xor(m, s2, 64));
      float e0 = expf(v0-m), e1 = expf(v1-m), e2 = expf(ve-m), e3 = expf(v3-m);
      float ss = (e0+e1)+(e2+e3);
      #pragma unroll
      for (int s2=32;s2>0;s2>>=1) ss += __shfl_xor(ss, s2, 64);
      float inv = 1.f/ss;
      att[r][h][lane] = e0*inv; att[r][h][lane+64] = e1*inv;
      att[r][h][lane+128] = e2*inv; att[r][h][lane+192] = e3*inv;
    }
  }
  __syncthreads();
  int c=(t&31)*4, ps=t>>5; int h2 = c>>5;
  {
    float4 acc[2];
    #pragma unroll
    for (int r=0;r<2;r++) acc[r]=make_float4(0.f,0.f,0.f,0.f);
    #pragma unroll 4
    for (int i=0;i<32;i++){
      int p = ps*32+i;
      float4 v = *(const float4*)&v2[((size_t)(b*PP)+p)*DD + c];
      #pragma unroll
      for (int r=0;r<2;r++) f4fma(acc[r], att[r][h2][p], v);
    }
    #pragma unroll
    for (int r=0;r<2;r++) *(float4*)&part[(ps*2+r)*DD+c]=acc[r];
  }
  __syncthreads();
  {
    int cc=t&127, r=t>>7;
    float s=0.f;
    #pragma unroll
    for (int k2_=0;k2_<8;k2_++) s+=part[(k2_*2+r)*DD+cc];
    o_l[r][cc]=s;
  }
  __syncthreads();
  {
    float4 a2[2];
    #pragma unroll
    for (int r=0;r<2;r++) a2[r]=make_float4(0.f,0.f,0.f,0.f);
    #pragma unroll 4
    for (int i=ps*16;i<ps*16+16;i++){
      float4 w = *(const float4*)&op_W[(size_t)i*DD + c];
      #pragma unroll
      for (int r=0;r<2;r++) f4fma(a2[r], o_l[r][i], w);
    }
    #pragma unroll
    for (int r=0;r<2;r++) *(float4*)&part[(ps*2+r)*DD+c]=a2[r];
  }
  __syncthreads();
  {
    int cc=t&127, r=t>>7;
    float s=0.f;
    #pragma unroll
    for (int k2_=0;k2_<8;k2_++) s+=part[(k2_*2+r)*DD+cc];
    float pv = s+op_b[cc];
    pnl[r][cc] = pv;
    pnew[(size_t)(r0+r)*DD+cc] = pv;
  }
  // ---- final MLP on same rows ----
  for (int i=t;i<2*(3*DD);i+=256){
    int r = i/(3*DD), cc = i%(3*DD);
    xs[r][cc] = agf[(size_t)(r0+r)*(3*DD)+cc];
  }
  __syncthreads();
  if (t < 2*DD){
    int r = t>>7, cc = t&127;
    xs[r][3*DD+cc] = pnl[r][cc];
  }
  __syncthreads();
  // stage1: (2 x 512) @ (512 x 256), KS=4, slice 128
  {
    int c1=(t&63)*4, ks1=t>>6;
    float4 acc[2];
    #pragma unroll
    for (int r=0;r<2;r++) acc[r]=make_float4(0.f,0.f,0.f,0.f);
    #pragma unroll 8
    for (int i=ks1*128;i<ks1*128+128;i++){
      float4 w = *(const float4*)&oW1[(size_t)i*HDIM+c1];
      #pragma unroll
      for (int r=0;r<2;r++) f4fma(acc[r], xs[r][i], w);
    }
    #pragma unroll
    for (int r=0;r<2;r++) *(float4*)&part[(ks1*2+r)*HDIM+c1]=acc[r];
  }
  __syncthreads();
  {
    float bv = ob1[t];
    #pragma unroll
    for (int r=0;r<2;r++){
      float s = (part[(0*2+r)*HDIM+t]+part[(1*2+r)*HDIM+t])
              + (part[(2*2+r)*HDIM+t]+part[(3*2+r)*HDIM+t]);
      hid[r][t] = fmaxf(s+bv, 0.f);
    }
  }
  __syncthreads();
  // stage2: (2 x 256) @ (256 x 128), KS=8, slice 32
  {
    float4 a2[2];
    #pragma unroll
    for (int r=0;r<2;r++) a2[r]=make_float4(0.f,0.f,0.f,0.f);
    #pragma unroll 8
    for (int h=ps*32;h<ps*32+32;h++){
      float4 w = *(const float4*)&oW2[(size_t)h*DD+c];
      #pragma unroll
      for (int r=0;r<2;r++) f4fma(a2[r], hid[r][h], w);
    }
    #pragma unroll
    for (int r=0;r<2;r++) *(float4*)&part[(ps*2+r)*DD+c]=a2[r];
  }
  __syncthreads();
  {
    int cc=t&127, r=t>>7;
    float s=0.f;
    #pragma unroll
    for (int k2_=0;k2_<8;k2_++) s+=part[(k2_*2+r)*DD+cc];
    anew[(size_t)(r0+r)*DD+cc]=s+ob2[cc];
  }
}

extern "C" void kernel_launch(void* const* d_in, const int* in_sizes, int n_in,
                              void* d_out, int out_size, void* d_ws, size_t ws_size,
                              hipStream_t stream) {
  const float* af       = (const float*)d_in[0];
  const float* at       = (const float*)d_in[1];
  const float* pf       = (const float*)d_in[2];
  const float* Hm       = (const float*)d_in[3];
  const float* type_emb = (const float*)d_in[4];
  const float* w_W1 = (const float*)d_in[5];
  const float* w_b1 = (const float*)d_in[6];
  const float* w_W2 = (const float*)d_in[7];
  const float* w_b2 = (const float*)d_in[8];
  const float* d_W1 = (const float*)d_in[9];
  const float* d_b1 = (const float*)d_in[10];
  const float* d_W2 = (const float*)d_in[11];
  const float* d_b2 = (const float*)d_in[12];
  const float* f_W1 = (const float*)d_in[13];
  const float* f_b1 = (const float*)d_in[14];
  const float* f_W2 = (const float*)d_in[15];
  const float* f_b2 = (const float*)d_in[16];
  const float* o_W1 = (const float*)d_in[17];
  const float* o_b1 = (const float*)d_in[18];
  const float* o_W2 = (const float*)d_in[19];
  const float* o_b2 = (const float*)d_in[20];
  const float* q_W  = (const float*)d_in[21];
  const float* q_b  = (const float*)d_in[22];
  const float* k_W  = (const float*)d_in[23];
  const float* k_b  = (const float*)d_in[24];
  const float* v_W  = (const float*)d_in[25];
  const float* v_b  = (const float*)d_in[26];
  const float* iq_W = (const float*)d_in[27];
  const float* iq_b = (const float*)d_in[28];
  const float* ik_W = (const float*)d_in[29];
  const float* ik_b = (const float*)d_in[30];
  const float* iv_W = (const float*)d_in[31];
  const float* iv_b = (const float*)d_in[32];
  const float* op_W = (const float*)d_in[33];
  const float* op_b = (const float*)d_in[34];

  float* ws   = (float*)d_ws;
  float* out  = (float*)d_out;
  float* anew = out;                 // (B,N,D)
  float* pnew = out + BB*NN*DD;      // (B,N,D)

  prep_kernel<<<GB_END, 256, 0, stream>>>(
      ws+WS_G, ws+WS_C0, w_b1, w_W2, w_b2,
      Hm, af, at, ws+WS_EF0, ws+WS_ETYPE, w_W1, ws+WS_V,
      pf, k_W,k_b,ik_W,ik_b, v_W,v_b,iv_W,iv_b,
      ws+WS_K2, ws+WS_V2);
  l1_fused_kernel<<<256,256,0,stream>>>(
      ws+WS_EF0, ws+WS_V, Hm, af, w_W1, w_b1, w_W2, w_b2, ws+WS_EDGEF);
  l2_fused_kernel<<<256,256,0,stream>>>(
      ws+WS_EDGEF, ws+WS_ETYPE, ws+WS_G,
      d_W1,d_b1,d_W2,d_b2, f_W1,f_b1,f_W2,f_b2, type_emb,
      w_W1, w_b1, w_W2, w_b2, ws+WS_C0, Hm, ws+WS_V,
      ws+WS_ETE, ws+WS_HWT);
  msgq2_kernel<<<BB*NN,256,0,stream>>>(
      ws+WS_HWT, ws+WS_EDGEF, ws+WS_ETE, af,
      q_W, q_b, iq_W, iq_b, ws+WS_AGF, ws+WS_Q2);
  attnfinal_kernel<<<256,256,0,stream>>>(
      ws+WS_Q2, ws+WS_K2, ws+WS_V2, op_W, op_b,
      ws+WS_AGF, o_W1,o_b1,o_W2,o_b2, pnew, anew);
}